// Round 1
// baseline (3450.431 us; speedup 1.0000x reference)
//
#include <hip/hip_runtime.h>
#include <hip/hip_bf16.h>

#define N_NODES 25000
#define N_EDGES 300000
#define IN_DIM  32
#define EDFD    16
#define HIDD    256
#define HEADS   4
#define NACT    16
#define NGRAPH  64
#define KWIRE   1024

// ---------------------------------------------------------------- helpers
__device__ __forceinline__ int fkey(float f) {
    int b = __float_as_int(f);
    b ^= (b >> 31) & 0x7fffffff;   // order-preserving map float -> int
    return b;
}
__device__ __forceinline__ float funkey(int b) {
    b ^= (b >> 31) & 0x7fffffff;   // involution
    return __int_as_float(b);
}
__device__ __forceinline__ float leaky(float v) { return v > 0.f ? v : 0.2f * v; }

// ---------------------------------------------------------------- NNConv
// T[n,j,o] = sum_i x[n,i] * w2[j, i*32+o];  xb[n,o] = sum_i x[n,i]*b2[i*32+o]
__global__ __launch_bounds__(256) void k_T(const float* __restrict__ x,
                                           const float* __restrict__ w2,
                                           const float* __restrict__ b2,
                                           float* __restrict__ T,
                                           float* __restrict__ xb) {
    __shared__ float xs[16][IN_DIM];
    int nb = blockIdx.x * 16;
    int t = threadIdx.x;
    for (int idx = t; idx < 16 * IN_DIM; idx += 256) {
        int m = idx >> 5, i = idx & 31;
        int n = nb + m;
        xs[m][i] = (n < N_NODES) ? x[n * IN_DIM + i] : 0.f;
    }
    __syncthreads();
    #pragma unroll
    for (int q = 0; q < 4; ++q) {
        int k = t + 256 * q;          // k = j*32 + o
        int j = k >> 5, o = k & 31;
        float acc[16];
        #pragma unroll
        for (int m = 0; m < 16; ++m) acc[m] = 0.f;
        for (int i = 0; i < IN_DIM; ++i) {
            float w = w2[j * 1024 + i * 32 + o];
            #pragma unroll
            for (int m = 0; m < 16; ++m) acc[m] += xs[m][i] * w;
        }
        #pragma unroll
        for (int m = 0; m < 16; ++m) {
            int n = nb + m;
            if (n < N_NODES) T[(size_t)n * 1024 + k] = acc[m];
        }
    }
    if (t < IN_DIM) {
        int o = t;
        for (int m = 0; m < 16; ++m) {
            int n = nb + m;
            if (n >= N_NODES) break;
            float s = 0.f;
            for (int i = 0; i < IN_DIM; ++i) s += xs[m][i] * b2[i * 32 + o];
            xb[n * IN_DIM + o] = s;
        }
    }
}

// per edge: h_j = relu(ea@w1+b1); msg_o = xb[src,o] + sum_j h_j*T[src,j,o]; scatter to agg[dst]
__global__ __launch_bounds__(256) void k_msg(const float* __restrict__ ea,
                                             const float* __restrict__ w1,
                                             const float* __restrict__ b1,
                                             const int* __restrict__ ei,
                                             const float* __restrict__ T,
                                             const float* __restrict__ xb,
                                             float* __restrict__ agg,
                                             float* __restrict__ cntf) {
    __shared__ float hb[8][IN_DIM];
    int t = threadIdx.x;
    int eg = t >> 5, o = t & 31;
    int e = blockIdx.x * 8 + eg;
    if (e < N_EDGES) {
        float a = b1[o];
        for (int k = 0; k < EDFD; ++k) a += ea[e * EDFD + k] * w1[k * 32 + o];
        hb[eg][o] = fmaxf(a, 0.f);
    }
    __syncthreads();
    if (e < N_EDGES) {
        int src = ei[e], dst = ei[N_EDGES + e];
        const float* Tp = T + (size_t)src * 1024;
        float m = xb[src * IN_DIM + o];
        #pragma unroll
        for (int j = 0; j < IN_DIM; ++j) m += hb[eg][j] * Tp[j * 32 + o];
        atomicAdd(&agg[dst * IN_DIM + o], m);
        if (o == 0) atomicAdd(&cntf[dst], 1.f);
    }
}

__global__ __launch_bounds__(256) void k_h0(const float* __restrict__ x,
                                            const float* __restrict__ root_w,
                                            const float* __restrict__ nn_bias,
                                            const float* __restrict__ agg,
                                            const float* __restrict__ cntf,
                                            float* __restrict__ h0) {
    int t = threadIdx.x;
    int ng = t >> 5, o = t & 31;
    int n = blockIdx.x * 8 + ng;
    if (n >= N_NODES) return;
    float s = nn_bias[o];
    for (int k = 0; k < IN_DIM; ++k) s += x[n * IN_DIM + k] * root_w[k * 32 + o];
    float c = fmaxf(cntf[n], 1.f);
    s += agg[n * IN_DIM + o] / c;
    h0[n * IN_DIM + o] = fmaxf(s, 0.f);
}

// ---------------------------------------------------------------- generic matmul C[N,1024] = A[N,K]@W[K,1024]
template <int K>
__global__ __launch_bounds__(256) void k_mm(const float* __restrict__ A,
                                            const float* __restrict__ W,
                                            float* __restrict__ C) {
    __shared__ float a_lds[32 * K];
    int t = threadIdx.x;
    int m0 = blockIdx.x * 32;
    int o = blockIdx.y * 256 + t;
    for (int idx = t; idx < 32 * K; idx += 256) {
        int r = idx / K, c = idx % K;
        int n = m0 + r;
        a_lds[idx] = (n < N_NODES) ? A[(size_t)n * K + c] : 0.f;
    }
    __syncthreads();
    float acc[32];
    #pragma unroll
    for (int m = 0; m < 32; ++m) acc[m] = 0.f;
    #pragma unroll 4
    for (int k = 0; k < K; ++k) {
        float w = W[(size_t)k * 1024 + o];
        #pragma unroll
        for (int m = 0; m < 32; ++m) acc[m] += a_lds[m * K + k] * w;
    }
    #pragma unroll
    for (int m = 0; m < 32; ++m) {
        int n = m0 + m;
        if (n < N_NODES) C[(size_t)n * 1024 + o] = acc[m];
    }
}

// es[n,h] = sum_d hf[n,h,d]*asrc[h,d]; ed likewise
__global__ __launch_bounds__(256) void k_esed(const float* __restrict__ hf,
                                              const float* __restrict__ asrc,
                                              const float* __restrict__ adst,
                                              float* __restrict__ es,
                                              float* __restrict__ ed) {
    int n = blockIdx.x;
    int h = threadIdx.x >> 6;
    int lane = threadIdx.x & 63;
    const float* hp = hf + (size_t)n * 1024 + h * 256;
    float s = 0.f, d2 = 0.f;
    for (int d = lane; d < 256; d += 64) {
        float v = hp[d];
        s  += v * asrc[h * 256 + d];
        d2 += v * adst[h * 256 + d];
    }
    #pragma unroll
    for (int off = 32; off; off >>= 1) {
        s  += __shfl_down(s, off);
        d2 += __shfl_down(d2, off);
    }
    if (lane == 0) { es[n * 4 + h] = s; ed[n * 4 + h] = d2; }
}

// m init from self loops (every node has one)
__global__ __launch_bounds__(256) void k_minit(const float* __restrict__ es,
                                               const float* __restrict__ ed,
                                               int* __restrict__ mkey) {
    int i = blockIdx.x * 256 + threadIdx.x;
    if (i >= N_NODES * 4) return;
    mkey[i] = fkey(leaky(es[i] + ed[i]));
}

__global__ __launch_bounds__(256) void k_mmax(const int* __restrict__ ei,
                                              const float* __restrict__ es,
                                              const float* __restrict__ ed,
                                              int* __restrict__ mkey) {
    int idx = blockIdx.x * 256 + threadIdx.x;   // e*4+h
    if (idx >= N_EDGES * 4) return;
    int e = idx >> 2, h = idx & 3;
    int src = ei[e], dst = ei[N_EDGES + e];
    atomicMax(&mkey[dst * 4 + h], fkey(leaky(es[src * 4 + h] + ed[dst * 4 + h])));
}

// unnormalized accumulation: outacc[dst] += w*hf[src]; den[dst] += w
__global__ __launch_bounds__(256) void k_acc(const int* __restrict__ ei,
                                             const float* __restrict__ es,
                                             const float* __restrict__ ed,
                                             const int* __restrict__ mkey,
                                             const float* __restrict__ hf,
                                             float* __restrict__ outacc,
                                             float* __restrict__ den) {
    int t = threadIdx.x;
    int unit = blockIdx.x * 4 + (t >> 6);   // (e2, h)
    int lane = t & 63;
    const int ne2 = N_EDGES + N_NODES;
    if (unit >= ne2 * HEADS) return;
    int e2 = unit >> 2, h = unit & 3;
    int src, dst;
    if (e2 < N_EDGES) { src = ei[e2]; dst = ei[N_EDGES + e2]; }
    else { src = e2 - N_EDGES; dst = src; }
    float v = leaky(es[src * 4 + h] + ed[dst * 4 + h]);
    float m = funkey(mkey[dst * 4 + h]);
    float w = __expf(v - m);
    if (lane == 0) atomicAdd(&den[dst * 4 + h], w);
    const float* hp = hf + (size_t)src * 1024 + h * 256;
    float* op = outacc + (size_t)dst * 1024 + h * 256;
    #pragma unroll
    for (int q = 0; q < 4; ++q) {
        int d = lane + q * 64;
        atomicAdd(&op[d], w * hp[d]);
    }
}

__global__ __launch_bounds__(256) void k_fin(const float* __restrict__ outacc,
                                             const float* __restrict__ den,
                                             const float* __restrict__ b,
                                             float* __restrict__ hout) {
    int i = blockIdx.x * 256 + threadIdx.x;  // n*256+d
    if (i >= N_NODES * HIDD) return;
    int n = i >> 8, d = i & 255;
    float s = 0.f;
    #pragma unroll
    for (int h = 0; h < 4; ++h)
        s += outacc[(size_t)n * 1024 + h * 256 + d] / (den[n * 4 + h] + 1e-16f);
    hout[i] = fmaxf(0.25f * s + b[d], 0.f);
}

// ---------------------------------------------------------------- heads
__global__ __launch_bounds__(256) void k_wire(const int* __restrict__ wm,
                                              const float* __restrict__ h2,
                                              const float* __restrict__ ww,
                                              const float* __restrict__ wb,
                                              float* __restrict__ out) {
    int k = blockIdx.x * 4 + (threadIdx.x >> 6);
    int lane = threadIdx.x & 63;
    if (k >= KWIRE) return;
    int n = wm[k];
    float s = 0.f;
    for (int d = lane; d < 256; d += 64) s += h2[(size_t)n * 256 + d] * ww[d];
    #pragma unroll
    for (int off = 32; off; off >>= 1) s += __shfl_down(s, off);
    if (lane == 0) out[k] = s + wb[0];
}

__global__ __launch_bounds__(256) void k_pool(const float* __restrict__ h2,
                                              const int* __restrict__ batch,
                                              float* __restrict__ pooled,
                                              float* __restrict__ gcnt) {
    int i = blockIdx.x * 256 + threadIdx.x;
    if (i >= N_NODES * HIDD) return;
    int n = i >> 8, d = i & 255;
    int g = batch[n];
    atomicAdd(&pooled[g * 256 + d], h2[i]);
    if (d == 0) atomicAdd(&gcnt[g], 1.f);
}

__global__ __launch_bounds__(256) void k_act(const float* __restrict__ pooled,
                                             const float* __restrict__ gcnt,
                                             const float* __restrict__ aw,
                                             const float* __restrict__ ab,
                                             float* __restrict__ out) {
    int u = blockIdx.x * 4 + (threadIdx.x >> 6);  // g*16+a
    int lane = threadIdx.x & 63;
    if (u >= NGRAPH * NACT) return;
    int g = u >> 4, a = u & 15;
    float c = fmaxf(gcnt[g], 1.f);
    float s = 0.f;
    for (int d = lane; d < 256; d += 64) s += pooled[g * 256 + d] * aw[d * 16 + a];
    #pragma unroll
    for (int off = 32; off; off >>= 1) s += __shfl_down(s, off);
    if (lane == 0) out[KWIRE + u] = s / c + ab[a];
}

// ---------------------------------------------------------------- launch
extern "C" void kernel_launch(void* const* d_in, const int* in_sizes, int n_in,
                              void* d_out, int out_size, void* d_ws, size_t ws_size,
                              hipStream_t stream) {
    const float* x        = (const float*)d_in[0];
    const float* edge_attr= (const float*)d_in[1];
    const int*   wire_mask= (const int*)d_in[2];
    const int*   edge_idx = (const int*)d_in[3];
    const int*   batch    = (const int*)d_in[4];
    const float* enc_w1   = (const float*)d_in[5];
    const float* enc_b1   = (const float*)d_in[6];
    const float* enc_w2   = (const float*)d_in[7];
    const float* enc_b2   = (const float*)d_in[8];
    const float* root_w   = (const float*)d_in[9];
    const float* nn_bias  = (const float*)d_in[10];
    const float* gat1_w   = (const float*)d_in[11];
    const float* gat1_asrc= (const float*)d_in[12];
    const float* gat1_adst= (const float*)d_in[13];
    const float* gat1_b   = (const float*)d_in[14];
    const float* gat2_w   = (const float*)d_in[15];
    const float* gat2_asrc= (const float*)d_in[16];
    const float* gat2_adst= (const float*)d_in[17];
    const float* gat2_b   = (const float*)d_in[18];
    const float* wire_w   = (const float*)d_in[19];
    const float* wire_b   = (const float*)d_in[20];
    const float* act_w    = (const float*)d_in[21];
    const float* act_b    = (const float*)d_in[22];
    float* out = (float*)d_out;

    float* ws = (float*)d_ws;
    size_t off = 0;
    float* T      = ws + off; off += 25600000;   // N*1024, aliased as outacc
    float* outacc = T;
    float* hfrag  = ws + off; off += 25600000;   // N*1024
    float* xb     = ws + off; off += 800000;     // N*32
    float* agg    = ws + off; off += 800000;     // N*32
    float* cntf   = ws + off; off += 25600;      // N (rounded)
    float* h0     = ws + off; off += 800000;
    float* esb    = ws + off; off += 100000;     // N*4
    float* edb    = ws + off; off += 100000;
    int*   mkey   = (int*)(ws + off); off += 100000;
    float* den    = ws + off; off += 100000;
    float* h1     = ws + off; off += 6400000;    // N*256
    float* h2     = ws + off; off += 6400000;
    float* pooled = ws + off; off += NGRAPH * 256;
    float* gcnt   = ws + off; off += NGRAPH;

    // ---- NNConv ----
    hipMemsetAsync(agg, 0, (800000 + 25600) * sizeof(float), stream);  // agg + cntf
    k_T<<<(N_NODES + 15) / 16, 256, 0, stream>>>(x, enc_w2, enc_b2, T, xb);
    k_msg<<<N_EDGES / 8, 256, 0, stream>>>(edge_attr, enc_w1, enc_b1, edge_idx, T, xb, agg, cntf);
    k_h0<<<N_NODES / 8, 256, 0, stream>>>(x, root_w, nn_bias, agg, cntf, h0);

    const int ne2 = N_EDGES + N_NODES;

    // ---- GAT layer 1 (h0 [N,32] -> h1 [N,256]) ----
    hipMemsetAsync(outacc, 0, (size_t)25600000 * sizeof(float), stream);
    hipMemsetAsync(den, 0, 100000 * sizeof(float), stream);
    {
        dim3 g(782, 4);
        k_mm<32><<<g, 256, 0, stream>>>(h0, gat1_w, hfrag);
    }
    k_esed<<<N_NODES, 256, 0, stream>>>(hfrag, gat1_asrc, gat1_adst, esb, edb);
    k_minit<<<(N_NODES * 4 + 255) / 256, 256, 0, stream>>>(esb, edb, mkey);
    k_mmax<<<(N_EDGES * 4 + 255) / 256, 256, 0, stream>>>(edge_idx, esb, edb, mkey);
    k_acc<<<ne2, 256, 0, stream>>>(edge_idx, esb, edb, mkey, hfrag, outacc, den);
    k_fin<<<N_NODES * HIDD / 256, 256, 0, stream>>>(outacc, den, gat1_b, h1);

    // ---- GAT layer 2 (h1 [N,256] -> h2 [N,256]) ----
    hipMemsetAsync(outacc, 0, (size_t)25600000 * sizeof(float), stream);
    hipMemsetAsync(den, 0, 100000 * sizeof(float), stream);
    {
        dim3 g(782, 4);
        k_mm<256><<<g, 256, 0, stream>>>(h1, gat2_w, hfrag);
    }
    k_esed<<<N_NODES, 256, 0, stream>>>(hfrag, gat2_asrc, gat2_adst, esb, edb);
    k_minit<<<(N_NODES * 4 + 255) / 256, 256, 0, stream>>>(esb, edb, mkey);
    k_mmax<<<(N_EDGES * 4 + 255) / 256, 256, 0, stream>>>(edge_idx, esb, edb, mkey);
    k_acc<<<ne2, 256, 0, stream>>>(edge_idx, esb, edb, mkey, hfrag, outacc, den);
    k_fin<<<N_NODES * HIDD / 256, 256, 0, stream>>>(outacc, den, gat2_b, h2);

    // ---- heads ----
    k_wire<<<KWIRE / 4, 256, 0, stream>>>(wire_mask, h2, wire_w, wire_b, out);
    hipMemsetAsync(pooled, 0, (NGRAPH * 256 + NGRAPH) * sizeof(float), stream);
    k_pool<<<N_NODES * HIDD / 256, 256, 0, stream>>>(h2, batch, pooled, gcnt);
    k_act<<<NGRAPH * NACT / 4, 256, 0, stream>>>(pooled, gcnt, act_w, act_b, out);
}

// Round 2
// 1606.990 us; speedup vs baseline: 2.1471x; 2.1471x over previous
//
#include <hip/hip_runtime.h>
#include <hip/hip_bf16.h>

#define N_NODES 25000
#define N_EDGES 300000
#define IN_DIM  32
#define EDFD    16
#define HIDD    256
#define HEADS   4
#define NACT    16
#define NGRAPH  64
#define KWIRE   1024

// ---------------------------------------------------------------- helpers
__device__ __forceinline__ float leaky(float v) { return v > 0.f ? v : 0.2f * v; }

// ---------------------------------------------------------------- CSR build
__global__ __launch_bounds__(256) void k_deg(const int* __restrict__ ei, int* __restrict__ deg) {
    int e = blockIdx.x * 256 + threadIdx.x;
    if (e >= N_EDGES) return;
    atomicAdd(&deg[ei[N_EDGES + e]], 1);
}

// single-block exclusive scan of deg[N_NODES] -> rowptr[N_NODES+1]
__global__ __launch_bounds__(256) void k_scan(const int* __restrict__ deg, int* __restrict__ rowptr) {
    __shared__ int part[256];
    int t = threadIdx.x;
    const int CH = 98;            // 256*98 = 25088 >= N_NODES
    int base = t * CH;
    int s = 0;
    for (int i = 0; i < CH; ++i) {
        int idx = base + i;
        if (idx < N_NODES) s += deg[idx];
    }
    part[t] = s;
    __syncthreads();
    if (t == 0) {
        int run = 0;
        for (int i = 0; i < 256; ++i) { int v = part[i]; part[i] = run; run += v; }
    }
    __syncthreads();
    int run = part[t];
    for (int i = 0; i < CH; ++i) {
        int idx = base + i;
        if (idx < N_NODES) { rowptr[idx] = run; run += deg[idx]; }
    }
    if (N_NODES >= base && N_NODES < base + CH) rowptr[N_NODES] = run;
}

__global__ __launch_bounds__(256) void k_scatter(const int* __restrict__ ei,
                                                 const int* __restrict__ rowptr,
                                                 int* __restrict__ cursor,
                                                 int* __restrict__ csrc) {
    int e = blockIdx.x * 256 + threadIdx.x;
    if (e >= N_EDGES) return;
    int dst = ei[N_EDGES + e];
    int pos = atomicAdd(&cursor[dst], 1);
    csrc[rowptr[dst] + pos] = ei[e];   // store src node id
}

// ---------------------------------------------------------------- NNConv
// T[n,j,o] = sum_i x[n,i] * w2[j, i*32+o];  xb[n,o] = sum_i x[n,i]*b2[i*32+o]
__global__ __launch_bounds__(256) void k_T(const float* __restrict__ x,
                                           const float* __restrict__ w2,
                                           const float* __restrict__ b2,
                                           float* __restrict__ T,
                                           float* __restrict__ xb) {
    __shared__ float xs[16][IN_DIM];
    int nb = blockIdx.x * 16;
    int t = threadIdx.x;
    for (int idx = t; idx < 16 * IN_DIM; idx += 256) {
        int m = idx >> 5, i = idx & 31;
        int n = nb + m;
        xs[m][i] = (n < N_NODES) ? x[n * IN_DIM + i] : 0.f;
    }
    __syncthreads();
    #pragma unroll
    for (int q = 0; q < 4; ++q) {
        int k = t + 256 * q;          // k = j*32 + o
        int j = k >> 5, o = k & 31;
        float acc[16];
        #pragma unroll
        for (int m = 0; m < 16; ++m) acc[m] = 0.f;
        for (int i = 0; i < IN_DIM; ++i) {
            float w = w2[j * 1024 + i * 32 + o];
            #pragma unroll
            for (int m = 0; m < 16; ++m) acc[m] += xs[m][i] * w;
        }
        #pragma unroll
        for (int m = 0; m < 16; ++m) {
            int n = nb + m;
            if (n < N_NODES) T[(size_t)n * 1024 + k] = acc[m];
        }
    }
    if (t < IN_DIM) {
        int o = t;
        for (int m = 0; m < 16; ++m) {
            int n = nb + m;
            if (n >= N_NODES) break;
            float s = 0.f;
            for (int i = 0; i < IN_DIM; ++i) s += xs[m][i] * b2[i * 32 + o];
            xb[n * IN_DIM + o] = s;
        }
    }
}

// per edge: h_j = relu(ea@w1+b1); msg_o = xb[src,o] + sum_j h_j*T[src,j,o]; scatter to agg[dst]
__global__ __launch_bounds__(256) void k_msg(const float* __restrict__ ea,
                                             const float* __restrict__ w1,
                                             const float* __restrict__ b1,
                                             const int* __restrict__ ei,
                                             const float* __restrict__ T,
                                             const float* __restrict__ xb,
                                             float* __restrict__ agg,
                                             float* __restrict__ cntf) {
    __shared__ float hb[8][IN_DIM];
    int t = threadIdx.x;
    int eg = t >> 5, o = t & 31;
    int e = blockIdx.x * 8 + eg;
    if (e < N_EDGES) {
        float a = b1[o];
        for (int k = 0; k < EDFD; ++k) a += ea[e * EDFD + k] * w1[k * 32 + o];
        hb[eg][o] = fmaxf(a, 0.f);
    }
    __syncthreads();
    if (e < N_EDGES) {
        int src = ei[e], dst = ei[N_EDGES + e];
        const float* Tp = T + (size_t)src * 1024;
        float m = xb[src * IN_DIM + o];
        #pragma unroll
        for (int j = 0; j < IN_DIM; ++j) m += hb[eg][j] * Tp[j * 32 + o];
        atomicAdd(&agg[dst * IN_DIM + o], m);
        if (o == 0) atomicAdd(&cntf[dst], 1.f);
    }
}

__global__ __launch_bounds__(256) void k_h0(const float* __restrict__ x,
                                            const float* __restrict__ root_w,
                                            const float* __restrict__ nn_bias,
                                            const float* __restrict__ agg,
                                            const float* __restrict__ cntf,
                                            float* __restrict__ h0) {
    int t = threadIdx.x;
    int ng = t >> 5, o = t & 31;
    int n = blockIdx.x * 8 + ng;
    if (n >= N_NODES) return;
    float s = nn_bias[o];
    for (int k = 0; k < IN_DIM; ++k) s += x[n * IN_DIM + k] * root_w[k * 32 + o];
    float c = fmaxf(cntf[n], 1.f);
    s += agg[n * IN_DIM + o] / c;
    h0[n * IN_DIM + o] = fmaxf(s, 0.f);
}

// ---------------------------------------------------------------- generic matmul C[N,1024] = A[N,K]@W[K,1024]
template <int K>
__global__ __launch_bounds__(256) void k_mm(const float* __restrict__ A,
                                            const float* __restrict__ W,
                                            float* __restrict__ C) {
    __shared__ float a_lds[32 * K];
    int t = threadIdx.x;
    int m0 = blockIdx.x * 32;
    int o = blockIdx.y * 256 + t;
    for (int idx = t; idx < 32 * K; idx += 256) {
        int r = idx / K, c = idx % K;
        int n = m0 + r;
        a_lds[idx] = (n < N_NODES) ? A[(size_t)n * K + c] : 0.f;
    }
    __syncthreads();
    float acc[32];
    #pragma unroll
    for (int m = 0; m < 32; ++m) acc[m] = 0.f;
    #pragma unroll 4
    for (int k = 0; k < K; ++k) {
        float w = W[(size_t)k * 1024 + o];
        #pragma unroll
        for (int m = 0; m < 32; ++m) acc[m] += a_lds[m * K + k] * w;
    }
    #pragma unroll
    for (int m = 0; m < 32; ++m) {
        int n = m0 + m;
        if (n < N_NODES) C[(size_t)n * 1024 + o] = acc[m];
    }
}

// es[n,h] = sum_d hf[n,h,d]*asrc[h,d]; ed likewise
__global__ __launch_bounds__(256) void k_esed(const float* __restrict__ hf,
                                              const float* __restrict__ asrc,
                                              const float* __restrict__ adst,
                                              float* __restrict__ es,
                                              float* __restrict__ ed) {
    int n = blockIdx.x;
    int h = threadIdx.x >> 6;
    int lane = threadIdx.x & 63;
    const float* hp = hf + (size_t)n * 1024 + h * 256;
    float s = 0.f, d2 = 0.f;
    for (int d = lane; d < 256; d += 64) {
        float v = hp[d];
        s  += v * asrc[h * 256 + d];
        d2 += v * adst[h * 256 + d];
    }
    #pragma unroll
    for (int off = 32; off; off >>= 1) {
        s  += __shfl_down(s, off);
        d2 += __shfl_down(d2, off);
    }
    if (lane == 0) { es[n * 4 + h] = s; ed[n * 4 + h] = d2; }
}

// fused GAT aggregation via CSR gather: one block per dst, wave h = head h.
// softmax-max, denom, weighted sum, head-mean, bias, relu -> hout
__global__ __launch_bounds__(256) void k_gat(const int* __restrict__ rowptr,
                                             const int* __restrict__ csrc,
                                             const float* __restrict__ es,
                                             const float* __restrict__ ed,
                                             const float* __restrict__ hf,
                                             const float* __restrict__ b,
                                             float* __restrict__ hout) {
    __shared__ float sm[4][256];
    int dst = blockIdx.x;
    int h = threadIdx.x >> 6, lane = threadIdx.x & 63;
    int r0 = rowptr[dst], r1 = rowptr[dst + 1];
    float edv = ed[dst * 4 + h];
    float vself = leaky(es[dst * 4 + h] + edv);
    // pass 1: segment max (self-loop + in-edges)
    float m = vself;
    for (int r = r0; r < r1; ++r) {
        int src = csrc[r];
        m = fmaxf(m, leaky(es[src * 4 + h] + edv));
    }
    // pass 2: accumulate
    float w = __expf(vself - m);
    float den = w;
    float4 hv = *((const float4*)(hf + (size_t)dst * 1024 + h * 256) + lane);
    float4 acc;
    acc.x = w * hv.x; acc.y = w * hv.y; acc.z = w * hv.z; acc.w = w * hv.w;
    for (int r = r0; r < r1; ++r) {
        int src = csrc[r];
        float v = leaky(es[src * 4 + h] + edv);
        w = __expf(v - m);
        den += w;
        float4 s = *((const float4*)(hf + (size_t)src * 1024 + h * 256) + lane);
        acc.x += w * s.x; acc.y += w * s.y; acc.z += w * s.z; acc.w += w * s.w;
    }
    float inv = 1.f / (den + 1e-16f);
    sm[h][lane * 4 + 0] = acc.x * inv;
    sm[h][lane * 4 + 1] = acc.y * inv;
    sm[h][lane * 4 + 2] = acc.z * inv;
    sm[h][lane * 4 + 3] = acc.w * inv;
    __syncthreads();
    int d = threadIdx.x;
    float s = 0.25f * (sm[0][d] + sm[1][d] + sm[2][d] + sm[3][d]) + b[d];
    hout[(size_t)dst * 256 + d] = fmaxf(s, 0.f);
}

// ---------------------------------------------------------------- heads
__global__ __launch_bounds__(256) void k_wire(const int* __restrict__ wm,
                                              const float* __restrict__ h2,
                                              const float* __restrict__ ww,
                                              const float* __restrict__ wb,
                                              float* __restrict__ out) {
    int k = blockIdx.x * 4 + (threadIdx.x >> 6);
    int lane = threadIdx.x & 63;
    if (k >= KWIRE) return;
    int n = wm[k];
    float s = 0.f;
    for (int d = lane; d < 256; d += 64) s += h2[(size_t)n * 256 + d] * ww[d];
    #pragma unroll
    for (int off = 32; off; off >>= 1) s += __shfl_down(s, off);
    if (lane == 0) out[k] = s + wb[0];
}

__global__ __launch_bounds__(256) void k_pool(const float* __restrict__ h2,
                                              const int* __restrict__ batch,
                                              float* __restrict__ pooled,
                                              float* __restrict__ gcnt) {
    int i = blockIdx.x * 256 + threadIdx.x;
    if (i >= N_NODES * HIDD) return;
    int n = i >> 8, d = i & 255;
    int g = batch[n];
    atomicAdd(&pooled[g * 256 + d], h2[i]);
    if (d == 0) atomicAdd(&gcnt[g], 1.f);
}

__global__ __launch_bounds__(256) void k_act(const float* __restrict__ pooled,
                                             const float* __restrict__ gcnt,
                                             const float* __restrict__ aw,
                                             const float* __restrict__ ab,
                                             float* __restrict__ out) {
    int u = blockIdx.x * 4 + (threadIdx.x >> 6);  // g*16+a
    int lane = threadIdx.x & 63;
    if (u >= NGRAPH * NACT) return;
    int g = u >> 4, a = u & 15;
    float c = fmaxf(gcnt[g], 1.f);
    float s = 0.f;
    for (int d = lane; d < 256; d += 64) s += pooled[g * 256 + d] * aw[d * 16 + a];
    #pragma unroll
    for (int off = 32; off; off >>= 1) s += __shfl_down(s, off);
    if (lane == 0) out[KWIRE + u] = s / c + ab[a];
}

// ---------------------------------------------------------------- launch
extern "C" void kernel_launch(void* const* d_in, const int* in_sizes, int n_in,
                              void* d_out, int out_size, void* d_ws, size_t ws_size,
                              hipStream_t stream) {
    const float* x        = (const float*)d_in[0];
    const float* edge_attr= (const float*)d_in[1];
    const int*   wire_mask= (const int*)d_in[2];
    const int*   edge_idx = (const int*)d_in[3];
    const int*   batch    = (const int*)d_in[4];
    const float* enc_w1   = (const float*)d_in[5];
    const float* enc_b1   = (const float*)d_in[6];
    const float* enc_w2   = (const float*)d_in[7];
    const float* enc_b2   = (const float*)d_in[8];
    const float* root_w   = (const float*)d_in[9];
    const float* nn_bias  = (const float*)d_in[10];
    const float* gat1_w   = (const float*)d_in[11];
    const float* gat1_asrc= (const float*)d_in[12];
    const float* gat1_adst= (const float*)d_in[13];
    const float* gat1_b   = (const float*)d_in[14];
    const float* gat2_w   = (const float*)d_in[15];
    const float* gat2_asrc= (const float*)d_in[16];
    const float* gat2_adst= (const float*)d_in[17];
    const float* gat2_b   = (const float*)d_in[18];
    const float* wire_w   = (const float*)d_in[19];
    const float* wire_b   = (const float*)d_in[20];
    const float* act_w    = (const float*)d_in[21];
    const float* act_b    = (const float*)d_in[22];
    float* out = (float*)d_out;

    float* ws = (float*)d_ws;
    size_t off = 0;
    float* T      = ws + off; off += 25600000;   // N*1024
    float* hfrag  = ws + off; off += 25600000;   // N*1024
    float* xb     = ws + off; off += 800000;     // N*32
    float* agg    = ws + off; off += 800000;     // N*32
    float* cntf   = ws + off; off += 25600;      // N (rounded)
    float* h0     = ws + off; off += 800000;
    float* esb    = ws + off; off += 100000;     // N*4
    float* edb    = ws + off; off += 100000;
    float* h1     = ws + off; off += 6400000;    // N*256
    float* h2     = ws + off; off += 6400000;
    float* pooled = ws + off; off += NGRAPH * 256;
    float* gcnt   = ws + off; off += NGRAPH;
    int* deg      = (int*)(ws + off); off += 25600;
    int* rowptr   = (int*)(ws + off); off += 25600;   // N+1
    int* cursor   = (int*)(ws + off); off += 25600;
    int* csrc     = (int*)(ws + off); off += N_EDGES;

    // ---- CSR build (by dst) ----
    hipMemsetAsync(deg, 0, 25600 * sizeof(int), stream);
    hipMemsetAsync(cursor, 0, 25600 * sizeof(int), stream);
    k_deg<<<(N_EDGES + 255) / 256, 256, 0, stream>>>(edge_idx, deg);
    k_scan<<<1, 256, 0, stream>>>(deg, rowptr);
    k_scatter<<<(N_EDGES + 255) / 256, 256, 0, stream>>>(edge_idx, rowptr, cursor, csrc);

    // ---- NNConv ----
    hipMemsetAsync(agg, 0, (800000 + 25600) * sizeof(float), stream);  // agg + cntf
    k_T<<<(N_NODES + 15) / 16, 256, 0, stream>>>(x, enc_w2, enc_b2, T, xb);
    k_msg<<<N_EDGES / 8, 256, 0, stream>>>(edge_attr, enc_w1, enc_b1, edge_idx, T, xb, agg, cntf);
    k_h0<<<N_NODES / 8, 256, 0, stream>>>(x, root_w, nn_bias, agg, cntf, h0);

    // ---- GAT layer 1 (h0 [N,32] -> h1 [N,256]) ----
    {
        dim3 g(782, 4);
        k_mm<32><<<g, 256, 0, stream>>>(h0, gat1_w, hfrag);
    }
    k_esed<<<N_NODES, 256, 0, stream>>>(hfrag, gat1_asrc, gat1_adst, esb, edb);
    k_gat<<<N_NODES, 256, 0, stream>>>(rowptr, csrc, esb, edb, hfrag, gat1_b, h1);

    // ---- GAT layer 2 (h1 [N,256] -> h2 [N,256]) ----
    {
        dim3 g(782, 4);
        k_mm<256><<<g, 256, 0, stream>>>(h1, gat2_w, hfrag);
    }
    k_esed<<<N_NODES, 256, 0, stream>>>(hfrag, gat2_asrc, gat2_adst, esb, edb);
    k_gat<<<N_NODES, 256, 0, stream>>>(rowptr, csrc, esb, edb, hfrag, gat2_b, h2);

    // ---- heads ----
    k_wire<<<KWIRE / 4, 256, 0, stream>>>(wire_mask, h2, wire_w, wire_b, out);
    hipMemsetAsync(pooled, 0, (NGRAPH * 256 + NGRAPH) * sizeof(float), stream);
    k_pool<<<N_NODES * HIDD / 256, 256, 0, stream>>>(h2, batch, pooled, gcnt);
    k_act<<<NGRAPH * NACT / 4, 256, 0, stream>>>(pooled, gcnt, act_w, act_b, out);
}

// Round 3
// 1213.030 us; speedup vs baseline: 2.8445x; 1.3248x over previous
//
#include <hip/hip_runtime.h>
#include <hip/hip_bf16.h>

#define N_NODES 25000
#define M_PAD   25024            // multiple of 16 (1564 tiles)
#define N_EDGES 300000
#define IN_DIM  32
#define EDFD    16
#define HIDD    256
#define HEADS   4
#define NACT    16
#define NGRAPH  64
#define KWIRE   1024

typedef __attribute__((ext_vector_type(8))) short short8v;
typedef __attribute__((ext_vector_type(4))) float f32x4;

// ---------------------------------------------------------------- helpers
__device__ __forceinline__ float leaky(float v) { return v > 0.f ? v : 0.2f * v; }
__device__ __forceinline__ unsigned short f2bf(float f) {
    unsigned int u = __float_as_uint(f);
    u += 0x7fff + ((u >> 16) & 1);           // round-to-nearest-even
    return (unsigned short)(u >> 16);
}
__device__ __forceinline__ float bf2f(unsigned short h) {
    return __uint_as_float(((unsigned int)h) << 16);
}

// ---------------------------------------------------------------- CSR build
__global__ __launch_bounds__(256) void k_deg(const int* __restrict__ ei, int* __restrict__ deg) {
    int e = blockIdx.x * 256 + threadIdx.x;
    if (e >= N_EDGES) return;
    atomicAdd(&deg[ei[N_EDGES + e]], 1);
}

__global__ __launch_bounds__(256) void k_scan(const int* __restrict__ deg, int* __restrict__ rowptr) {
    __shared__ int part[256];
    int t = threadIdx.x;
    const int CH = 98;
    int base = t * CH;
    int s = 0;
    for (int i = 0; i < CH; ++i) {
        int idx = base + i;
        if (idx < N_NODES) s += deg[idx];
    }
    part[t] = s;
    __syncthreads();
    if (t == 0) {
        int run = 0;
        for (int i = 0; i < 256; ++i) { int v = part[i]; part[i] = run; run += v; }
    }
    __syncthreads();
    int run = part[t];
    for (int i = 0; i < CH; ++i) {
        int idx = base + i;
        if (idx < N_NODES) { rowptr[idx] = run; run += deg[idx]; }
    }
    if (N_NODES >= base && N_NODES < base + CH) rowptr[N_NODES] = run;
}

__global__ __launch_bounds__(256) void k_scatter(const int* __restrict__ ei,
                                                 const int* __restrict__ rowptr,
                                                 int* __restrict__ cursor,
                                                 int* __restrict__ csrc) {
    int e = blockIdx.x * 256 + threadIdx.x;
    if (e >= N_EDGES) return;
    int dst = ei[N_EDGES + e];
    int pos = atomicAdd(&cursor[dst], 1);
    csrc[rowptr[dst] + pos] = ei[e];
}

// ---------------------------------------------------------------- weight split/transpose
// W[K][1024] fp32 -> Wh/Wl [1024][K] bf16 (hi/lo split)
template <int K>
__global__ __launch_bounds__(256) void k_wsplit(const float* __restrict__ W,
                                                unsigned short* __restrict__ Wh,
                                                unsigned short* __restrict__ Wl) {
    int i = blockIdx.x * 256 + threadIdx.x;
    if (i >= K * 1024) return;
    int k = i >> 10, n = i & 1023;
    float w = W[i];
    unsigned short hi = f2bf(w);
    Wh[n * K + k] = hi;
    Wl[n * K + k] = f2bf(w - bf2f(hi));
}

// ---------------------------------------------------------------- NNConv
__global__ __launch_bounds__(256) void k_T(const float* __restrict__ x,
                                           const float* __restrict__ w2,
                                           const float* __restrict__ b2,
                                           float* __restrict__ T,
                                           float* __restrict__ xb) {
    __shared__ float xs[16][IN_DIM];
    int nb = blockIdx.x * 16;
    int t = threadIdx.x;
    for (int idx = t; idx < 16 * IN_DIM; idx += 256) {
        int m = idx >> 5, i = idx & 31;
        int n = nb + m;
        xs[m][i] = (n < N_NODES) ? x[n * IN_DIM + i] : 0.f;
    }
    __syncthreads();
    #pragma unroll
    for (int q = 0; q < 4; ++q) {
        int k = t + 256 * q;
        int j = k >> 5, o = k & 31;
        float acc[16];
        #pragma unroll
        for (int m = 0; m < 16; ++m) acc[m] = 0.f;
        for (int i = 0; i < IN_DIM; ++i) {
            float w = w2[j * 1024 + i * 32 + o];
            #pragma unroll
            for (int m = 0; m < 16; ++m) acc[m] += xs[m][i] * w;
        }
        #pragma unroll
        for (int m = 0; m < 16; ++m) {
            int n = nb + m;
            if (n < N_NODES) T[(size_t)n * 1024 + k] = acc[m];
        }
    }
    if (t < IN_DIM) {
        int o = t;
        for (int m = 0; m < 16; ++m) {
            int n = nb + m;
            if (n >= N_NODES) break;
            float s = 0.f;
            for (int i = 0; i < IN_DIM; ++i) s += xs[m][i] * b2[i * 32 + o];
            xb[n * IN_DIM + o] = s;
        }
    }
}

__global__ __launch_bounds__(256) void k_msg(const float* __restrict__ ea,
                                             const float* __restrict__ w1,
                                             const float* __restrict__ b1,
                                             const int* __restrict__ ei,
                                             const float* __restrict__ T,
                                             const float* __restrict__ xb,
                                             float* __restrict__ agg,
                                             float* __restrict__ cntf) {
    __shared__ float hb[8][IN_DIM];
    int t = threadIdx.x;
    int eg = t >> 5, o = t & 31;
    int e = blockIdx.x * 8 + eg;
    if (e < N_EDGES) {
        float a = b1[o];
        for (int k = 0; k < EDFD; ++k) a += ea[e * EDFD + k] * w1[k * 32 + o];
        hb[eg][o] = fmaxf(a, 0.f);
    }
    __syncthreads();
    if (e < N_EDGES) {
        int src = ei[e], dst = ei[N_EDGES + e];
        const float* Tp = T + (size_t)src * 1024;
        float m = xb[src * IN_DIM + o];
        #pragma unroll
        for (int j = 0; j < IN_DIM; ++j) m += hb[eg][j] * Tp[j * 32 + o];
        atomicAdd(&agg[dst * IN_DIM + o], m);
        if (o == 0) atomicAdd(&cntf[dst], 1.f);
    }
}

// h0 = relu(agg/cnt + x@root_w + bias)  -> emit bf16 hi/lo only
__global__ __launch_bounds__(256) void k_h0(const float* __restrict__ x,
                                            const float* __restrict__ root_w,
                                            const float* __restrict__ nn_bias,
                                            const float* __restrict__ agg,
                                            const float* __restrict__ cntf,
                                            unsigned short* __restrict__ ah,
                                            unsigned short* __restrict__ al) {
    int t = threadIdx.x;
    int ng = t >> 5, o = t & 31;
    int n = blockIdx.x * 8 + ng;
    if (n >= N_NODES) return;
    float s = nn_bias[o];
    for (int k = 0; k < IN_DIM; ++k) s += x[n * IN_DIM + k] * root_w[k * 32 + o];
    float c = fmaxf(cntf[n], 1.f);
    s += agg[n * IN_DIM + o] / c;
    float v = fmaxf(s, 0.f);
    unsigned short hi = f2bf(v);
    ah[n * IN_DIM + o] = hi;
    al[n * IN_DIM + o] = f2bf(v - bf2f(hi));
}

// ---------------------------------------------------------------- split-bf16 MFMA GEMM
// C[M_PAD,1024] = A[M_PAD,K] @ W[K,1024];  A as hi/lo bf16 [M_PAD][K], W as hi/lo bf16 [1024][K] (transposed).
// grid: x = 8 (128-col blocks, wave -> 32-col strip), y = m-chunks of MT tiles.
template <int K, int MT>
__global__ __launch_bounds__(256, 2) void k_mfmm(const unsigned short* __restrict__ Ah,
                                                 const unsigned short* __restrict__ Al,
                                                 const unsigned short* __restrict__ Wh,
                                                 const unsigned short* __restrict__ Wl,
                                                 float* __restrict__ C) {
    constexpr int KS = K / 32;
    int wid = threadIdx.x >> 6, lane = threadIdx.x & 63;
    int lr = lane & 15;              // row (A) / col (B) within 16-tile
    int lk = (lane >> 4) * 8;        // k offset within 32
    int n0 = blockIdx.x * 128 + wid * 32;

    short8v bh[KS][2], bl[KS][2];
    #pragma unroll
    for (int ks = 0; ks < KS; ++ks) {
        #pragma unroll
        for (int c = 0; c < 2; ++c) {
            size_t boff = (size_t)(n0 + c * 16 + lr) * K + ks * 32 + lk;
            bh[ks][c] = *(const short8v*)(Wh + boff);
            bl[ks][c] = *(const short8v*)(Wl + boff);
        }
    }

    int t0 = blockIdx.y * MT;
    int t1 = t0 + MT; if (t1 > M_PAD / 16) t1 = M_PAD / 16;
    for (int t = t0; t < t1; ++t) {
        int m0 = t * 16;
        const unsigned short* ar = Ah + (size_t)(m0 + lr) * K + lk;
        const unsigned short* arl = Al + (size_t)(m0 + lr) * K + lk;
        short8v ah[KS], al[KS];
        #pragma unroll
        for (int ks = 0; ks < KS; ++ks) {
            ah[ks] = *(const short8v*)(ar + ks * 32);
            al[ks] = *(const short8v*)(arl + ks * 32);
        }
        f32x4 acc[2] = {{0.f,0.f,0.f,0.f},{0.f,0.f,0.f,0.f}};
        #pragma unroll
        for (int ks = 0; ks < KS; ++ks) {
            #pragma unroll
            for (int c = 0; c < 2; ++c) {
                acc[c] = __builtin_amdgcn_mfma_f32_16x16x32_bf16(ah[ks], bh[ks][c], acc[c], 0, 0, 0);
                acc[c] = __builtin_amdgcn_mfma_f32_16x16x32_bf16(ah[ks], bl[ks][c], acc[c], 0, 0, 0);
                acc[c] = __builtin_amdgcn_mfma_f32_16x16x32_bf16(al[ks], bh[ks][c], acc[c], 0, 0, 0);
            }
        }
        int rbase = (lane >> 4) * 4;
        #pragma unroll
        for (int c = 0; c < 2; ++c) {
            #pragma unroll
            for (int r = 0; r < 4; ++r)
                C[(size_t)(m0 + rbase + r) * 1024 + n0 + c * 16 + lr] = acc[c][r];
        }
    }
}

// ---------------------------------------------------------------- GAT attention pieces
__global__ __launch_bounds__(256) void k_esed(const float* __restrict__ hf,
                                              const float* __restrict__ asrc,
                                              const float* __restrict__ adst,
                                              float* __restrict__ es,
                                              float* __restrict__ ed) {
    int n = blockIdx.x;
    int h = threadIdx.x >> 6;
    int lane = threadIdx.x & 63;
    const float* hp = hf + (size_t)n * 1024 + h * 256;
    float s = 0.f, d2 = 0.f;
    for (int d = lane; d < 256; d += 64) {
        float v = hp[d];
        s  += v * asrc[h * 256 + d];
        d2 += v * adst[h * 256 + d];
    }
    #pragma unroll
    for (int off = 32; off; off >>= 1) {
        s  += __shfl_down(s, off);
        d2 += __shfl_down(d2, off);
    }
    if (lane == 0) { es[n * 4 + h] = s; ed[n * 4 + h] = d2; }
}

// fused GAT aggregation; optionally emits fp32 and/or bf16 hi/lo outputs
template <bool EMIT_F32, bool EMIT_BF>
__global__ __launch_bounds__(256) void k_gat(const int* __restrict__ rowptr,
                                             const int* __restrict__ csrc,
                                             const float* __restrict__ es,
                                             const float* __restrict__ ed,
                                             const float* __restrict__ hf,
                                             const float* __restrict__ b,
                                             float* __restrict__ hout,
                                             unsigned short* __restrict__ oh,
                                             unsigned short* __restrict__ ol) {
    __shared__ float sm[4][256];
    int dst = blockIdx.x;
    int h = threadIdx.x >> 6, lane = threadIdx.x & 63;
    int r0 = rowptr[dst], r1 = rowptr[dst + 1];
    float edv = ed[dst * 4 + h];
    float vself = leaky(es[dst * 4 + h] + edv);
    float m = vself;
    for (int r = r0; r < r1; ++r) {
        int src = csrc[r];
        m = fmaxf(m, leaky(es[src * 4 + h] + edv));
    }
    float w = __expf(vself - m);
    float den = w;
    float4 hv = *((const float4*)(hf + (size_t)dst * 1024 + h * 256) + lane);
    float4 acc;
    acc.x = w * hv.x; acc.y = w * hv.y; acc.z = w * hv.z; acc.w = w * hv.w;
    for (int r = r0; r < r1; ++r) {
        int src = csrc[r];
        float v = leaky(es[src * 4 + h] + edv);
        w = __expf(v - m);
        den += w;
        float4 s = *((const float4*)(hf + (size_t)src * 1024 + h * 256) + lane);
        acc.x += w * s.x; acc.y += w * s.y; acc.z += w * s.z; acc.w += w * s.w;
    }
    float inv = 1.f / (den + 1e-16f);
    sm[h][lane * 4 + 0] = acc.x * inv;
    sm[h][lane * 4 + 1] = acc.y * inv;
    sm[h][lane * 4 + 2] = acc.z * inv;
    sm[h][lane * 4 + 3] = acc.w * inv;
    __syncthreads();
    int d = threadIdx.x;
    float s = 0.25f * (sm[0][d] + sm[1][d] + sm[2][d] + sm[3][d]) + b[d];
    float v = fmaxf(s, 0.f);
    if (EMIT_F32) hout[(size_t)dst * 256 + d] = v;
    if (EMIT_BF) {
        unsigned short hi = f2bf(v);
        oh[(size_t)dst * 256 + d] = hi;
        ol[(size_t)dst * 256 + d] = f2bf(v - bf2f(hi));
    }
}

// ---------------------------------------------------------------- heads
__global__ __launch_bounds__(256) void k_wire(const int* __restrict__ wm,
                                              const float* __restrict__ h2,
                                              const float* __restrict__ ww,
                                              const float* __restrict__ wb,
                                              float* __restrict__ out) {
    int k = blockIdx.x * 4 + (threadIdx.x >> 6);
    int lane = threadIdx.x & 63;
    if (k >= KWIRE) return;
    int n = wm[k];
    float s = 0.f;
    for (int d = lane; d < 256; d += 64) s += h2[(size_t)n * 256 + d] * ww[d];
    #pragma unroll
    for (int off = 32; off; off >>= 1) s += __shfl_down(s, off);
    if (lane == 0) out[k] = s + wb[0];
}

__global__ __launch_bounds__(256) void k_pool(const float* __restrict__ h2,
                                              const int* __restrict__ batch,
                                              float* __restrict__ pooled,
                                              float* __restrict__ gcnt) {
    int i = blockIdx.x * 256 + threadIdx.x;
    if (i >= N_NODES * HIDD) return;
    int n = i >> 8, d = i & 255;
    int g = batch[n];
    atomicAdd(&pooled[g * 256 + d], h2[i]);
    if (d == 0) atomicAdd(&gcnt[g], 1.f);
}

__global__ __launch_bounds__(256) void k_act(const float* __restrict__ pooled,
                                             const float* __restrict__ gcnt,
                                             const float* __restrict__ aw,
                                             const float* __restrict__ ab,
                                             float* __restrict__ out) {
    int u = blockIdx.x * 4 + (threadIdx.x >> 6);
    int lane = threadIdx.x & 63;
    if (u >= NGRAPH * NACT) return;
    int g = u >> 4, a = u & 15;
    float c = fmaxf(gcnt[g], 1.f);
    float s = 0.f;
    for (int d = lane; d < 256; d += 64) s += pooled[g * 256 + d] * aw[d * 16 + a];
    #pragma unroll
    for (int off = 32; off; off >>= 1) s += __shfl_down(s, off);
    if (lane == 0) out[KWIRE + u] = s / c + ab[a];
}

// ---------------------------------------------------------------- launch
extern "C" void kernel_launch(void* const* d_in, const int* in_sizes, int n_in,
                              void* d_out, int out_size, void* d_ws, size_t ws_size,
                              hipStream_t stream) {
    const float* x        = (const float*)d_in[0];
    const float* edge_attr= (const float*)d_in[1];
    const int*   wire_mask= (const int*)d_in[2];
    const int*   edge_idx = (const int*)d_in[3];
    const int*   batch    = (const int*)d_in[4];
    const float* enc_w1   = (const float*)d_in[5];
    const float* enc_b1   = (const float*)d_in[6];
    const float* enc_w2   = (const float*)d_in[7];
    const float* enc_b2   = (const float*)d_in[8];
    const float* root_w   = (const float*)d_in[9];
    const float* nn_bias  = (const float*)d_in[10];
    const float* gat1_w   = (const float*)d_in[11];
    const float* gat1_asrc= (const float*)d_in[12];
    const float* gat1_adst= (const float*)d_in[13];
    const float* gat1_b   = (const float*)d_in[14];
    const float* gat2_w   = (const float*)d_in[15];
    const float* gat2_asrc= (const float*)d_in[16];
    const float* gat2_adst= (const float*)d_in[17];
    const float* gat2_b   = (const float*)d_in[18];
    const float* wire_w   = (const float*)d_in[19];
    const float* wire_b   = (const float*)d_in[20];
    const float* act_w    = (const float*)d_in[21];
    const float* act_b    = (const float*)d_in[22];
    float* out = (float*)d_out;

    float* ws = (float*)d_ws;
    size_t off = 0;
    float* T      = ws + off; off += 25600000;      // 102.4 MB; after k_msg, aliased below
    float* hfrag  = ws + off; off += (size_t)M_PAD * 1024;   // GEMM output
    float* xb     = ws + off; off += 800000;
    float* agg    = ws + off; off += 800000;
    float* cntf   = ws + off; off += 25600;
    float* esb    = ws + off; off += 100000;
    float* edb    = ws + off; off += 100000;
    float* h2     = ws + off; off += 6400000;
    float* pooled = ws + off; off += NGRAPH * 256;
    float* gcnt   = ws + off; off += NGRAPH;
    int* deg      = (int*)(ws + off); off += 25600;
    int* rowptr   = (int*)(ws + off); off += 25600;
    int* cursor   = (int*)(ws + off); off += 25600;
    int* csrc     = (int*)(ws + off); off += N_EDGES;
    unsigned short* w1h = (unsigned short*)(ws + off); off += 16384;  // 32x1024 bf16
    unsigned short* w1l = (unsigned short*)(ws + off); off += 16384;
    unsigned short* w2h = (unsigned short*)(ws + off); off += 131072; // 256x1024 bf16
    unsigned short* w2l = (unsigned short*)(ws + off); off += 131072;

    // aliases inside T (dead after k_msg): A hi/lo for both GEMMs
    unsigned short* ah0 = (unsigned short*)T;                 // [M_PAD][32]
    unsigned short* al0 = ah0 + (size_t)M_PAD * IN_DIM;
    unsigned short* h1h = al0 + (size_t)M_PAD * IN_DIM;       // [M_PAD][256]
    unsigned short* h1l = h1h + (size_t)M_PAD * HIDD;

    // ---- CSR build (by dst) ----
    hipMemsetAsync(deg, 0, 25600 * sizeof(int), stream);
    hipMemsetAsync(cursor, 0, 25600 * sizeof(int), stream);
    k_deg<<<(N_EDGES + 255) / 256, 256, 0, stream>>>(edge_idx, deg);
    k_scan<<<1, 256, 0, stream>>>(deg, rowptr);
    k_scatter<<<(N_EDGES + 255) / 256, 256, 0, stream>>>(edge_idx, rowptr, cursor, csrc);

    // ---- weight split/transpose ----
    k_wsplit<IN_DIM><<<(IN_DIM * 1024 + 255) / 256, 256, 0, stream>>>(gat1_w, w1h, w1l);
    k_wsplit<HIDD><<<(HIDD * 1024 + 255) / 256, 256, 0, stream>>>(gat2_w, w2h, w2l);

    // ---- NNConv ----
    hipMemsetAsync(agg, 0, (800000 + 25600) * sizeof(float), stream);
    k_T<<<(N_NODES + 15) / 16, 256, 0, stream>>>(x, enc_w2, enc_b2, T, xb);
    k_msg<<<N_EDGES / 8, 256, 0, stream>>>(edge_attr, enc_w1, enc_b1, edge_idx, T, xb, agg, cntf);

    // T is now dead: zero pad rows of the aliased bf16 buffers
    hipMemsetAsync(ah0 + (size_t)N_NODES * IN_DIM, 0, (M_PAD - N_NODES) * IN_DIM * 2, stream);
    hipMemsetAsync(al0 + (size_t)N_NODES * IN_DIM, 0, (M_PAD - N_NODES) * IN_DIM * 2, stream);
    hipMemsetAsync(h1h + (size_t)N_NODES * HIDD, 0, (M_PAD - N_NODES) * HIDD * 2, stream);
    hipMemsetAsync(h1l + (size_t)N_NODES * HIDD, 0, (M_PAD - N_NODES) * HIDD * 2, stream);

    k_h0<<<N_NODES / 8, 256, 0, stream>>>(x, root_w, nn_bias, agg, cntf, ah0, al0);

    // ---- GAT layer 1: hfrag = h0 @ gat1_w  (MFMA split-bf16) ----
    {
        dim3 g(8, (M_PAD / 16 + 24) / 25);
        k_mfmm<IN_DIM, 25><<<g, 256, 0, stream>>>(ah0, al0, w1h, w1l, hfrag);
    }
    k_esed<<<N_NODES, 256, 0, stream>>>(hfrag, gat1_asrc, gat1_adst, esb, edb);
    k_gat<false, true><<<N_NODES, 256, 0, stream>>>(rowptr, csrc, esb, edb, hfrag, gat1_b,
                                                    nullptr, h1h, h1l);

    // ---- GAT layer 2: hfrag = h1 @ gat2_w ----
    {
        dim3 g(8, (M_PAD / 16 + 24) / 25);
        k_mfmm<HIDD, 25><<<g, 256, 0, stream>>>(h1h, h1l, w2h, w2l, hfrag);
    }
    k_esed<<<N_NODES, 256, 0, stream>>>(hfrag, gat2_asrc, gat2_adst, esb, edb);
    k_gat<true, false><<<N_NODES, 256, 0, stream>>>(rowptr, csrc, esb, edb, hfrag, gat2_b,
                                                    h2, nullptr, nullptr);

    // ---- heads ----
    k_wire<<<KWIRE / 4, 256, 0, stream>>>(wire_mask, h2, wire_w, wire_b, out);
    hipMemsetAsync(pooled, 0, (NGRAPH * 256 + NGRAPH) * sizeof(float), stream);
    k_pool<<<N_NODES * HIDD / 256, 256, 0, stream>>>(h2, batch, pooled, gcnt);
    k_act<<<NGRAPH * NACT / 4, 256, 0, stream>>>(pooled, gcnt, act_w, act_b, out);
}

// Round 6
// 1012.387 us; speedup vs baseline: 3.4082x; 1.1982x over previous
//
#include <hip/hip_runtime.h>
#include <hip/hip_bf16.h>

#define N_NODES 25000
#define M_PAD   25024            // multiple of 16 (1564 tiles)
#define N_EDGES 300000
#define IN_DIM  32
#define EDFD    16
#define HIDD    256
#define HEADS   4
#define NACT    16
#define NGRAPH  64
#define KWIRE   1024
#define POOL_NB 64               // nodes per pooling block

typedef __attribute__((ext_vector_type(8))) short short8v;
typedef __attribute__((ext_vector_type(4))) float f32x4;

// ---------------------------------------------------------------- helpers
__device__ __forceinline__ float leaky(float v) { return v > 0.f ? v : 0.2f * v; }
__device__ __forceinline__ unsigned short f2bf(float f) {
    unsigned int u = __float_as_uint(f);
    u += 0x7fff + ((u >> 16) & 1);           // round-to-nearest-even
    return (unsigned short)(u >> 16);
}
__device__ __forceinline__ float bf2f(unsigned short h) {
    return __uint_as_float(((unsigned int)h) << 16);
}

// ---------------------------------------------------------------- CSR build
__global__ __launch_bounds__(256) void k_deg(const int* __restrict__ ei, int* __restrict__ deg) {
    int e = blockIdx.x * 256 + threadIdx.x;
    if (e >= N_EDGES) return;
    atomicAdd(&deg[ei[N_EDGES + e]], 1);
}

__global__ __launch_bounds__(256) void k_scan(const int* __restrict__ deg, int* __restrict__ rowptr) {
    __shared__ int part[256];
    int t = threadIdx.x;
    const int CH = 98;
    int base = t * CH;
    int s = 0;
    for (int i = 0; i < CH; ++i) {
        int idx = base + i;
        if (idx < N_NODES) s += deg[idx];
    }
    part[t] = s;
    __syncthreads();
    if (t == 0) {
        int run = 0;
        for (int i = 0; i < 256; ++i) { int v = part[i]; part[i] = run; run += v; }
    }
    __syncthreads();
    int run = part[t];
    for (int i = 0; i < CH; ++i) {
        int idx = base + i;
        if (idx < N_NODES) { rowptr[idx] = run; run += deg[idx]; }
    }
    if (N_NODES >= base && N_NODES < base + CH) rowptr[N_NODES] = run;
}

__global__ __launch_bounds__(256) void k_scatter(const int* __restrict__ ei,
                                                 const int* __restrict__ rowptr,
                                                 int* __restrict__ cursor,
                                                 int* __restrict__ csrc) {
    int e = blockIdx.x * 256 + threadIdx.x;
    if (e >= N_EDGES) return;
    int dst = ei[N_EDGES + e];
    int pos = atomicAdd(&cursor[dst], 1);
    csrc[rowptr[dst] + pos] = ei[e];
}

// ---------------------------------------------------------------- weight split/transpose
// W[K][1024] fp32 -> Wh/Wl [1024][K] bf16 (hi/lo split)
template <int K>
__global__ __launch_bounds__(256) void k_wsplit(const float* __restrict__ W,
                                                unsigned short* __restrict__ Wh,
                                                unsigned short* __restrict__ Wl) {
    int i = blockIdx.x * 256 + threadIdx.x;
    if (i >= K * 1024) return;
    int k = i >> 10, n = i & 1023;
    float w = W[i];
    unsigned short hi = f2bf(w);
    Wh[n * K + k] = hi;
    Wl[n * K + k] = f2bf(w - bf2f(hi));
}

// ---------------------------------------------------------------- NNConv
__global__ __launch_bounds__(256) void k_T(const float* __restrict__ x,
                                           const float* __restrict__ w2,
                                           const float* __restrict__ b2,
                                           float* __restrict__ T,
                                           float* __restrict__ xb) {
    __shared__ float xs[16][IN_DIM];
    int nb = blockIdx.x * 16;
    int t = threadIdx.x;
    for (int idx = t; idx < 16 * IN_DIM; idx += 256) {
        int m = idx >> 5, i = idx & 31;
        int n = nb + m;
        xs[m][i] = (n < N_NODES) ? x[n * IN_DIM + i] : 0.f;
    }
    __syncthreads();
    #pragma unroll
    for (int q = 0; q < 4; ++q) {
        int k = t + 256 * q;
        int j = k >> 5, o = k & 31;
        float acc[16];
        #pragma unroll
        for (int m = 0; m < 16; ++m) acc[m] = 0.f;
        for (int i = 0; i < IN_DIM; ++i) {
            float w = w2[j * 1024 + i * 32 + o];
            #pragma unroll
            for (int m = 0; m < 16; ++m) acc[m] += xs[m][i] * w;
        }
        #pragma unroll
        for (int m = 0; m < 16; ++m) {
            int n = nb + m;
            if (n < N_NODES) T[(size_t)n * 1024 + k] = acc[m];
        }
    }
    if (t < IN_DIM) {
        int o = t;
        for (int m = 0; m < 16; ++m) {
            int n = nb + m;
            if (n >= N_NODES) break;
            float s = 0.f;
            for (int i = 0; i < IN_DIM; ++i) s += xs[m][i] * b2[i * 32 + o];
            xb[n * IN_DIM + o] = s;
        }
    }
}

__global__ __launch_bounds__(256) void k_msg(const float* __restrict__ ea,
                                             const float* __restrict__ w1,
                                             const float* __restrict__ b1,
                                             const int* __restrict__ ei,
                                             const float* __restrict__ T,
                                             const float* __restrict__ xb,
                                             float* __restrict__ agg,
                                             float* __restrict__ cntf) {
    __shared__ float hb[8][IN_DIM];
    int t = threadIdx.x;
    int eg = t >> 5, o = t & 31;
    int e = blockIdx.x * 8 + eg;
    if (e < N_EDGES) {
        float a = b1[o];
        for (int k = 0; k < EDFD; ++k) a += ea[e * EDFD + k] * w1[k * 32 + o];
        hb[eg][o] = fmaxf(a, 0.f);
    }
    __syncthreads();
    if (e < N_EDGES) {
        int src = ei[e], dst = ei[N_EDGES + e];
        const float* Tp = T + (size_t)src * 1024;
        float m = xb[src * IN_DIM + o];
        #pragma unroll
        for (int j = 0; j < IN_DIM; ++j) m += hb[eg][j] * Tp[j * 32 + o];
        atomicAdd(&agg[dst * IN_DIM + o], m);
        if (o == 0) atomicAdd(&cntf[dst], 1.f);
    }
}

// h0 = relu(agg/cnt + x@root_w + bias)  -> emit bf16 hi/lo only
__global__ __launch_bounds__(256) void k_h0(const float* __restrict__ x,
                                            const float* __restrict__ root_w,
                                            const float* __restrict__ nn_bias,
                                            const float* __restrict__ agg,
                                            const float* __restrict__ cntf,
                                            unsigned short* __restrict__ ah,
                                            unsigned short* __restrict__ al) {
    int t = threadIdx.x;
    int ng = t >> 5, o = t & 31;
    int n = blockIdx.x * 8 + ng;
    if (n >= N_NODES) return;
    float s = nn_bias[o];
    for (int k = 0; k < IN_DIM; ++k) s += x[n * IN_DIM + k] * root_w[k * 32 + o];
    float c = fmaxf(cntf[n], 1.f);
    s += agg[n * IN_DIM + o] / c;
    float v = fmaxf(s, 0.f);
    unsigned short hi = f2bf(v);
    ah[n * IN_DIM + o] = hi;
    al[n * IN_DIM + o] = f2bf(v - bf2f(hi));
}

// ---------------------------------------------------------------- split-bf16 MFMA GEMM
// C[M_PAD,1024] = A[M_PAD,K] @ W[K,1024];  A as hi/lo bf16 [M_PAD][K], W as hi/lo bf16 [1024][K] (transposed).
// grid: x = 8 (128-col blocks, wave -> 32-col strip), y = m-chunks of MT tiles.
template <int K, int MT>
__global__ __launch_bounds__(256, 2) void k_mfmm(const unsigned short* __restrict__ Ah,
                                                 const unsigned short* __restrict__ Al,
                                                 const unsigned short* __restrict__ Wh,
                                                 const unsigned short* __restrict__ Wl,
                                                 float* __restrict__ C) {
    constexpr int KS = K / 32;
    int wid = threadIdx.x >> 6, lane = threadIdx.x & 63;
    int lr = lane & 15;              // row (A) / col (B) within 16-tile
    int lk = (lane >> 4) * 8;        // k offset within 32
    int n0 = blockIdx.x * 128 + wid * 32;

    short8v bh[KS][2], bl[KS][2];
    #pragma unroll
    for (int ks = 0; ks < KS; ++ks) {
        #pragma unroll
        for (int c = 0; c < 2; ++c) {
            size_t boff = (size_t)(n0 + c * 16 + lr) * K + ks * 32 + lk;
            bh[ks][c] = *(const short8v*)(Wh + boff);
            bl[ks][c] = *(const short8v*)(Wl + boff);
        }
    }

    int t0 = blockIdx.y * MT;
    int t1 = t0 + MT; if (t1 > M_PAD / 16) t1 = M_PAD / 16;
    for (int t = t0; t < t1; ++t) {
        int m0 = t * 16;
        const unsigned short* ar = Ah + (size_t)(m0 + lr) * K + lk;
        const unsigned short* arl = Al + (size_t)(m0 + lr) * K + lk;
        short8v ah[KS], al[KS];
        #pragma unroll
        for (int ks = 0; ks < KS; ++ks) {
            ah[ks] = *(const short8v*)(ar + ks * 32);
            al[ks] = *(const short8v*)(arl + ks * 32);
        }
        f32x4 acc[2] = {{0.f,0.f,0.f,0.f},{0.f,0.f,0.f,0.f}};
        #pragma unroll
        for (int ks = 0; ks < KS; ++ks) {
            #pragma unroll
            for (int c = 0; c < 2; ++c) {
                acc[c] = __builtin_amdgcn_mfma_f32_16x16x32_bf16(ah[ks], bh[ks][c], acc[c], 0, 0, 0);
                acc[c] = __builtin_amdgcn_mfma_f32_16x16x32_bf16(ah[ks], bl[ks][c], acc[c], 0, 0, 0);
                acc[c] = __builtin_amdgcn_mfma_f32_16x16x32_bf16(al[ks], bh[ks][c], acc[c], 0, 0, 0);
            }
        }
        int rbase = (lane >> 4) * 4;
        #pragma unroll
        for (int c = 0; c < 2; ++c) {
            #pragma unroll
            for (int r = 0; r < 4; ++r)
                C[(size_t)(m0 + rbase + r) * 1024 + n0 + c * 16 + lr] = acc[c][r];
        }
    }
}

// ---------------------------------------------------------------- GAT attention pieces
__global__ __launch_bounds__(256) void k_esed(const float* __restrict__ hf,
                                              const float* __restrict__ asrc,
                                              const float* __restrict__ adst,
                                              float* __restrict__ es,
                                              float* __restrict__ ed) {
    int n = blockIdx.x;
    int h = threadIdx.x >> 6;
    int lane = threadIdx.x & 63;
    const float* hp = hf + (size_t)n * 1024 + h * 256;
    float s = 0.f, d2 = 0.f;
    for (int d = lane; d < 256; d += 64) {
        float v = hp[d];
        s  += v * asrc[h * 256 + d];
        d2 += v * adst[h * 256 + d];
    }
    #pragma unroll
    for (int off = 32; off; off >>= 1) {
        s  += __shfl_down(s, off);
        d2 += __shfl_down(d2, off);
    }
    if (lane == 0) { es[n * 4 + h] = s; ed[n * 4 + h] = d2; }
}

// fused GAT aggregation; optionally emits fp32 and/or bf16 hi/lo outputs
template <bool EMIT_F32, bool EMIT_BF>
__global__ __launch_bounds__(256) void k_gat(const int* __restrict__ rowptr,
                                             const int* __restrict__ csrc,
                                             const float* __restrict__ es,
                                             const float* __restrict__ ed,
                                             const float* __restrict__ hf,
                                             const float* __restrict__ b,
                                             float* __restrict__ hout,
                                             unsigned short* __restrict__ oh,
                                             unsigned short* __restrict__ ol) {
    __shared__ float sm[4][256];
    int dst = blockIdx.x;
    int h = threadIdx.x >> 6, lane = threadIdx.x & 63;
    int r0 = rowptr[dst], r1 = rowptr[dst + 1];
    float edv = ed[dst * 4 + h];
    float vself = leaky(es[dst * 4 + h] + edv);
    float m = vself;
    for (int r = r0; r < r1; ++r) {
        int src = csrc[r];
        m = fmaxf(m, leaky(es[src * 4 + h] + edv));
    }
    float w = __expf(vself - m);
    float den = w;
    float4 hv = *((const float4*)(hf + (size_t)dst * 1024 + h * 256) + lane);
    float4 acc;
    acc.x = w * hv.x; acc.y = w * hv.y; acc.z = w * hv.z; acc.w = w * hv.w;
    for (int r = r0; r < r1; ++r) {
        int src = csrc[r];
        float v = leaky(es[src * 4 + h] + edv);
        w = __expf(v - m);
        den += w;
        float4 s = *((const float4*)(hf + (size_t)src * 1024 + h * 256) + lane);
        acc.x += w * s.x; acc.y += w * s.y; acc.z += w * s.z; acc.w += w * s.w;
    }
    float inv = 1.f / (den + 1e-16f);
    sm[h][lane * 4 + 0] = acc.x * inv;
    sm[h][lane * 4 + 1] = acc.y * inv;
    sm[h][lane * 4 + 2] = acc.z * inv;
    sm[h][lane * 4 + 3] = acc.w * inv;
    __syncthreads();
    int d = threadIdx.x;
    float s = 0.25f * (sm[0][d] + sm[1][d] + sm[2][d] + sm[3][d]) + b[d];
    float v = fmaxf(s, 0.f);
    if (EMIT_F32) hout[(size_t)dst * 256 + d] = v;
    if (EMIT_BF) {
        unsigned short hi = f2bf(v);
        oh[(size_t)dst * 256 + d] = hi;
        ol[(size_t)dst * 256 + d] = f2bf(v - bf2f(hi));
    }
}

// ---------------------------------------------------------------- heads
__global__ __launch_bounds__(256) void k_wire(const int* __restrict__ wm,
                                              const float* __restrict__ h2,
                                              const float* __restrict__ ww,
                                              const float* __restrict__ wb,
                                              float* __restrict__ out) {
    int k = blockIdx.x * 4 + (threadIdx.x >> 6);
    int lane = threadIdx.x & 63;
    if (k >= KWIRE) return;
    int n = wm[k];
    float s = 0.f;
    for (int d = lane; d < 256; d += 64) s += h2[(size_t)n * 256 + d] * ww[d];
    #pragma unroll
    for (int off = 32; off; off >>= 1) s += __shfl_down(s, off);
    if (lane == 0) out[k] = s + wb[0];
}

// segmented pooling: batch is sorted, so accumulate runs in registers and
// flush one atomicAdd per (segment, dim) at graph boundaries.
__global__ __launch_bounds__(256) void k_pool(const float* __restrict__ h2,
                                              const int* __restrict__ batch,
                                              float* __restrict__ pooled,
                                              float* __restrict__ gcnt) {
    int n0 = blockIdx.x * POOL_NB;
    int n1 = n0 + POOL_NB; if (n1 > N_NODES) n1 = N_NODES;
    int d = threadIdx.x;
    int cur = batch[n0];
    float acc = 0.f, cnt = 0.f;
    for (int n = n0; n < n1; ++n) {
        int g = batch[n];
        if (g != cur) {
            atomicAdd(&pooled[cur * 256 + d], acc);
            if (d == 0) atomicAdd(&gcnt[cur], cnt);
            acc = 0.f; cnt = 0.f; cur = g;
        }
        acc += h2[(size_t)n * 256 + d];
        cnt += 1.f;
    }
    atomicAdd(&pooled[cur * 256 + d], acc);
    if (d == 0) atomicAdd(&gcnt[cur], cnt);
}

__global__ __launch_bounds__(256) void k_act(const float* __restrict__ pooled,
                                             const float* __restrict__ gcnt,
                                             const float* __restrict__ aw,
                                             const float* __restrict__ ab,
                                             float* __restrict__ out) {
    int u = blockIdx.x * 4 + (threadIdx.x >> 6);
    int lane = threadIdx.x & 63;
    if (u >= NGRAPH * NACT) return;
    int g = u >> 4, a = u & 15;
    float c = fmaxf(gcnt[g], 1.f);
    float s = 0.f;
    for (int d = lane; d < 256; d += 64) s += pooled[g * 256 + d] * aw[d * 16 + a];
    #pragma unroll
    for (int off = 32; off; off >>= 1) s += __shfl_down(s, off);
    if (lane == 0) out[KWIRE + u] = s / c + ab[a];
}

// ---------------------------------------------------------------- launch
extern "C" void kernel_launch(void* const* d_in, const int* in_sizes, int n_in,
                              void* d_out, int out_size, void* d_ws, size_t ws_size,
                              hipStream_t stream) {
    const float* x        = (const float*)d_in[0];
    const float* edge_attr= (const float*)d_in[1];
    const int*   wire_mask= (const int*)d_in[2];
    const int*   edge_idx = (const int*)d_in[3];
    const int*   batch    = (const int*)d_in[4];
    const float* enc_w1   = (const float*)d_in[5];
    const float* enc_b1   = (const float*)d_in[6];
    const float* enc_w2   = (const float*)d_in[7];
    const float* enc_b2   = (const float*)d_in[8];
    const float* root_w   = (const float*)d_in[9];
    const float* nn_bias  = (const float*)d_in[10];
    const float* gat1_w   = (const float*)d_in[11];
    const float* gat1_asrc= (const float*)d_in[12];
    const float* gat1_adst= (const float*)d_in[13];
    const float* gat1_b   = (const float*)d_in[14];
    const float* gat2_w   = (const float*)d_in[15];
    const float* gat2_asrc= (const float*)d_in[16];
    const float* gat2_adst= (const float*)d_in[17];
    const float* gat2_b   = (const float*)d_in[18];
    const float* wire_w   = (const float*)d_in[19];
    const float* wire_b   = (const float*)d_in[20];
    const float* act_w    = (const float*)d_in[21];
    const float* act_b    = (const float*)d_in[22];
    float* out = (float*)d_out;

    float* ws = (float*)d_ws;
    size_t off = 0;
    float* T      = ws + off; off += 25600000;      // 102.4 MB; after k_msg, aliased below
    float* hfrag  = ws + off; off += (size_t)M_PAD * 1024;   // GEMM output
    float* xb     = ws + off; off += 800000;
    float* agg    = ws + off; off += 800000;
    float* cntf   = ws + off; off += 25600;
    float* esb    = ws + off; off += 100000;
    float* edb    = ws + off; off += 100000;
    float* h2     = ws + off; off += 6400000;
    float* pooled = ws + off; off += NGRAPH * 256;
    float* gcnt   = ws + off; off += NGRAPH;
    int* deg      = (int*)(ws + off); off += 25600;
    int* rowptr   = (int*)(ws + off); off += 25600;
    int* cursor   = (int*)(ws + off); off += 25600;
    int* csrc     = (int*)(ws + off); off += N_EDGES;
    unsigned short* w1h = (unsigned short*)(ws + off); off += 16384;  // 32x1024 bf16
    unsigned short* w1l = (unsigned short*)(ws + off); off += 16384;
    unsigned short* w2h = (unsigned short*)(ws + off); off += 131072; // 256x1024 bf16
    unsigned short* w2l = (unsigned short*)(ws + off); off += 131072;

    // aliases inside T (dead after k_msg): A hi/lo for both GEMMs
    unsigned short* ah0 = (unsigned short*)T;                 // [M_PAD][32]
    unsigned short* al0 = ah0 + (size_t)M_PAD * IN_DIM;
    unsigned short* h1h = al0 + (size_t)M_PAD * IN_DIM;       // [M_PAD][256]
    unsigned short* h1l = h1h + (size_t)M_PAD * HIDD;

    // ---- CSR build (by dst) ----
    hipMemsetAsync(deg, 0, 25600 * sizeof(int), stream);
    hipMemsetAsync(cursor, 0, 25600 * sizeof(int), stream);
    k_deg<<<(N_EDGES + 255) / 256, 256, 0, stream>>>(edge_idx, deg);
    k_scan<<<1, 256, 0, stream>>>(deg, rowptr);
    k_scatter<<<(N_EDGES + 255) / 256, 256, 0, stream>>>(edge_idx, rowptr, cursor, csrc);

    // ---- weight split/transpose ----
    k_wsplit<IN_DIM><<<(IN_DIM * 1024 + 255) / 256, 256, 0, stream>>>(gat1_w, w1h, w1l);
    k_wsplit<HIDD><<<(HIDD * 1024 + 255) / 256, 256, 0, stream>>>(gat2_w, w2h, w2l);

    // ---- NNConv ----
    hipMemsetAsync(agg, 0, (800000 + 25600) * sizeof(float), stream);
    k_T<<<(N_NODES + 15) / 16, 256, 0, stream>>>(x, enc_w2, enc_b2, T, xb);
    k_msg<<<N_EDGES / 8, 256, 0, stream>>>(edge_attr, enc_w1, enc_b1, edge_idx, T, xb, agg, cntf);

    // T is now dead: zero pad rows of the aliased bf16 buffers
    hipMemsetAsync(ah0 + (size_t)N_NODES * IN_DIM, 0, (M_PAD - N_NODES) * IN_DIM * 2, stream);
    hipMemsetAsync(al0 + (size_t)N_NODES * IN_DIM, 0, (M_PAD - N_NODES) * IN_DIM * 2, stream);
    hipMemsetAsync(h1h + (size_t)N_NODES * HIDD, 0, (M_PAD - N_NODES) * HIDD * 2, stream);
    hipMemsetAsync(h1l + (size_t)N_NODES * HIDD, 0, (M_PAD - N_NODES) * HIDD * 2, stream);

    k_h0<<<N_NODES / 8, 256, 0, stream>>>(x, root_w, nn_bias, agg, cntf, ah0, al0);

    // ---- GAT layer 1: hfrag = h0 @ gat1_w  (MFMA split-bf16) ----
    {
        dim3 g(8, (M_PAD / 16 + 24) / 25);
        k_mfmm<IN_DIM, 25><<<g, 256, 0, stream>>>(ah0, al0, w1h, w1l, hfrag);
    }
    k_esed<<<N_NODES, 256, 0, stream>>>(hfrag, gat1_asrc, gat1_adst, esb, edb);
    k_gat<false, true><<<N_NODES, 256, 0, stream>>>(rowptr, csrc, esb, edb, hfrag, gat1_b,
                                                    nullptr, h1h, h1l);

    // ---- GAT layer 2: hfrag = h1 @ gat2_w ----
    {
        dim3 g(8, (M_PAD / 16 + 24) / 25);
        k_mfmm<HIDD, 25><<<g, 256, 0, stream>>>(h1h, h1l, w2h, w2l, hfrag);
    }
    k_esed<<<N_NODES, 256, 0, stream>>>(hfrag, gat2_asrc, gat2_adst, esb, edb);
    k_gat<true, false><<<N_NODES, 256, 0, stream>>>(rowptr, csrc, esb, edb, hfrag, gat2_b,
                                                    h2, nullptr, nullptr);

    // ---- heads ----
    k_wire<<<KWIRE / 4, 256, 0, stream>>>(wire_mask, h2, wire_w, wire_b, out);
    hipMemsetAsync(pooled, 0, (NGRAPH * 256 + NGRAPH) * sizeof(float), stream);
    k_pool<<<(N_NODES + POOL_NB - 1) / POOL_NB, 256, 0, stream>>>(h2, batch, pooled, gcnt);
    k_act<<<NGRAPH * NACT / 4, 256, 0, stream>>>(pooled, gcnt, act_w, act_b, out);
}

// Round 7
// 692.721 us; speedup vs baseline: 4.9810x; 1.4615x over previous
//
#include <hip/hip_runtime.h>
#include <hip/hip_bf16.h>
#include <hip/hip_fp16.h>

#define N_NODES 25000
#define M_PAD   25024            // multiple of 16 (1564 tiles)
#define N_EDGES 300000
#define IN_DIM  32
#define EDFD    16
#define HIDD    256
#define HEADS   4
#define NACT    16
#define NGRAPH  64
#define KWIRE   1024
#define POOL_NB 64               // nodes per pooling block

typedef __attribute__((ext_vector_type(8))) short short8v;
typedef __attribute__((ext_vector_type(4))) float f32x4;

// ---------------------------------------------------------------- helpers
__device__ __forceinline__ float leaky(float v) { return v > 0.f ? v : 0.2f * v; }
__device__ __forceinline__ unsigned short f2bf(float f) {
    unsigned int u = __float_as_uint(f);
    u += 0x7fff + ((u >> 16) & 1);           // round-to-nearest-even
    return (unsigned short)(u >> 16);
}
__device__ __forceinline__ float bf2f(unsigned short h) {
    return __uint_as_float(((unsigned int)h) << 16);
}

template <typename T> __device__ __forceinline__ T cvt_out(float v);
template <> __device__ __forceinline__ float  cvt_out<float>(float v)  { return v; }
template <> __device__ __forceinline__ __half cvt_out<__half>(float v) { return __float2half(v); }

// ---------------------------------------------------------------- CSR build
__global__ __launch_bounds__(256) void k_deg(const int* __restrict__ ei, int* __restrict__ deg) {
    int e = blockIdx.x * 256 + threadIdx.x;
    if (e >= N_EDGES) return;
    atomicAdd(&deg[ei[N_EDGES + e]], 1);
}

__global__ __launch_bounds__(256) void k_scan(const int* __restrict__ deg, int* __restrict__ rowptr) {
    __shared__ int part[256];
    int t = threadIdx.x;
    const int CH = 98;
    int base = t * CH;
    int s = 0;
    for (int i = 0; i < CH; ++i) {
        int idx = base + i;
        if (idx < N_NODES) s += deg[idx];
    }
    part[t] = s;
    __syncthreads();
    if (t == 0) {
        int run = 0;
        for (int i = 0; i < 256; ++i) { int v = part[i]; part[i] = run; run += v; }
    }
    __syncthreads();
    int run = part[t];
    for (int i = 0; i < CH; ++i) {
        int idx = base + i;
        if (idx < N_NODES) { rowptr[idx] = run; run += deg[idx]; }
    }
    if (N_NODES >= base && N_NODES < base + CH) rowptr[N_NODES] = run;
}

__global__ __launch_bounds__(256) void k_scatter(const int* __restrict__ ei,
                                                 const int* __restrict__ rowptr,
                                                 int* __restrict__ cursor,
                                                 int* __restrict__ csrc) {
    int e = blockIdx.x * 256 + threadIdx.x;
    if (e >= N_EDGES) return;
    int dst = ei[N_EDGES + e];
    int pos = atomicAdd(&cursor[dst], 1);
    csrc[rowptr[dst] + pos] = ei[e];
}

// ---------------------------------------------------------------- weight prep
// W[K][1024] fp32 -> Wh/Wl [1024][K] bf16 (hi/lo split, transposed)
template <int K>
__global__ __launch_bounds__(256) void k_wsplit(const float* __restrict__ W,
                                                unsigned short* __restrict__ Wh,
                                                unsigned short* __restrict__ Wl) {
    int i = blockIdx.x * 256 + threadIdx.x;
    if (i >= K * 1024) return;
    int k = i >> 10, n = i & 1023;
    float w = W[i];
    unsigned short hi = f2bf(w);
    Wh[n * K + k] = hi;
    Wl[n * K + k] = f2bf(w - bf2f(hi));
}

// enc_w2 [32][1024] (j, i*32+o) -> W2t hi/lo [1024][32]: W2t[k=j*32+o][i]
__global__ __launch_bounds__(256) void k_w2perm(const float* __restrict__ w2,
                                                unsigned short* __restrict__ Wh,
                                                unsigned short* __restrict__ Wl) {
    int idx = blockIdx.x * 256 + threadIdx.x;   // k*32 + i
    if (idx >= 32 * 1024) return;
    int k = idx >> 5, i = idx & 31;
    float w = w2[(k >> 5) * 1024 + i * 32 + (k & 31)];
    unsigned short hi = f2bf(w);
    Wh[idx] = hi;
    Wl[idx] = f2bf(w - bf2f(hi));
}

// x [N][32] fp32 -> xh/xl bf16 + xb[n,o] = sum_i x[n,i]*b2[i*32+o]
__global__ __launch_bounds__(256) void k_xsplit(const float* __restrict__ x,
                                                const float* __restrict__ b2,
                                                unsigned short* __restrict__ xh,
                                                unsigned short* __restrict__ xl,
                                                float* __restrict__ xb) {
    int idx = blockIdx.x * 256 + threadIdx.x;
    if (idx >= N_NODES * 32) return;
    int n = idx >> 5, o = idx & 31;
    float v = x[idx];
    unsigned short hi = f2bf(v);
    xh[idx] = hi;
    xl[idx] = f2bf(v - bf2f(hi));
    float s = 0.f;
    for (int i = 0; i < 32; ++i) s += x[n * 32 + i] * b2[i * 32 + o];
    xb[idx] = s;
}

// ---------------------------------------------------------------- NNConv edge pass
// per edge: h_j = relu(ea@w1+b1); msg_o = xb[src,o] + sum_j h_j*T[src,j,o]; scatter to agg[dst]
__global__ __launch_bounds__(256) void k_msg(const float* __restrict__ ea,
                                             const float* __restrict__ w1,
                                             const float* __restrict__ b1,
                                             const int* __restrict__ ei,
                                             const __half* __restrict__ T,
                                             const float* __restrict__ xb,
                                             float* __restrict__ agg,
                                             float* __restrict__ cntf) {
    __shared__ float hb[8][IN_DIM];
    int t = threadIdx.x;
    int eg = t >> 5, o = t & 31;
    int e = blockIdx.x * 8 + eg;
    if (e < N_EDGES) {
        float a = b1[o];
        for (int k = 0; k < EDFD; ++k) a += ea[e * EDFD + k] * w1[k * 32 + o];
        hb[eg][o] = fmaxf(a, 0.f);
    }
    __syncthreads();
    if (e < N_EDGES) {
        int src = ei[e], dst = ei[N_EDGES + e];
        const __half* Tp = T + (size_t)src * 1024;
        float m = xb[src * IN_DIM + o];
        #pragma unroll
        for (int j = 0; j < IN_DIM; ++j) m += hb[eg][j] * __half2float(Tp[j * 32 + o]);
        atomicAdd(&agg[dst * IN_DIM + o], m);
        if (o == 0) atomicAdd(&cntf[dst], 1.f);
    }
}

// h0 = relu(agg/cnt + x@root_w + bias)  -> emit bf16 hi/lo
__global__ __launch_bounds__(256) void k_h0(const float* __restrict__ x,
                                            const float* __restrict__ root_w,
                                            const float* __restrict__ nn_bias,
                                            const float* __restrict__ agg,
                                            const float* __restrict__ cntf,
                                            unsigned short* __restrict__ ah,
                                            unsigned short* __restrict__ al) {
    int t = threadIdx.x;
    int ng = t >> 5, o = t & 31;
    int n = blockIdx.x * 8 + ng;
    if (n >= N_NODES) return;
    float s = nn_bias[o];
    for (int k = 0; k < IN_DIM; ++k) s += x[n * IN_DIM + k] * root_w[k * 32 + o];
    float c = fmaxf(cntf[n], 1.f);
    s += agg[n * IN_DIM + o] / c;
    float v = fmaxf(s, 0.f);
    unsigned short hi = f2bf(v);
    ah[n * IN_DIM + o] = hi;
    al[n * IN_DIM + o] = f2bf(v - bf2f(hi));
}

// ---------------------------------------------------------------- split-bf16 MFMA GEMM
// C[M_PAD,1024] = A[M_PAD,K] @ W[K,1024];  A hi/lo bf16 [M_PAD][K], W hi/lo bf16 [1024][K] (transposed).
// grid: x = 8 (128-col blocks, wave -> 32-col strip), y = m-chunks of MT tiles. CT = float or __half.
template <int K, int MT, typename CT>
__global__ __launch_bounds__(256, 2) void k_mfmm(const unsigned short* __restrict__ Ah,
                                                 const unsigned short* __restrict__ Al,
                                                 const unsigned short* __restrict__ Wh,
                                                 const unsigned short* __restrict__ Wl,
                                                 CT* __restrict__ C) {
    constexpr int KS = K / 32;
    int wid = threadIdx.x >> 6, lane = threadIdx.x & 63;
    int lr = lane & 15;              // row (A) / col (B) within 16-tile
    int lk = (lane >> 4) * 8;        // k offset within 32
    int n0 = blockIdx.x * 128 + wid * 32;

    short8v bh[KS][2], bl[KS][2];
    #pragma unroll
    for (int ks = 0; ks < KS; ++ks) {
        #pragma unroll
        for (int c = 0; c < 2; ++c) {
            size_t boff = (size_t)(n0 + c * 16 + lr) * K + ks * 32 + lk;
            bh[ks][c] = *(const short8v*)(Wh + boff);
            bl[ks][c] = *(const short8v*)(Wl + boff);
        }
    }

    int t0 = blockIdx.y * MT;
    int t1 = t0 + MT; if (t1 > M_PAD / 16) t1 = M_PAD / 16;
    for (int t = t0; t < t1; ++t) {
        int m0 = t * 16;
        const unsigned short* ar  = Ah + (size_t)(m0 + lr) * K + lk;
        const unsigned short* arl = Al + (size_t)(m0 + lr) * K + lk;
        short8v ah[KS], al[KS];
        #pragma unroll
        for (int ks = 0; ks < KS; ++ks) {
            ah[ks] = *(const short8v*)(ar + ks * 32);
            al[ks] = *(const short8v*)(arl + ks * 32);
        }
        f32x4 acc[2] = {{0.f,0.f,0.f,0.f},{0.f,0.f,0.f,0.f}};
        #pragma unroll
        for (int ks = 0; ks < KS; ++ks) {
            #pragma unroll
            for (int c = 0; c < 2; ++c) {
                acc[c] = __builtin_amdgcn_mfma_f32_16x16x32_bf16(ah[ks], bh[ks][c], acc[c], 0, 0, 0);
                acc[c] = __builtin_amdgcn_mfma_f32_16x16x32_bf16(ah[ks], bl[ks][c], acc[c], 0, 0, 0);
                acc[c] = __builtin_amdgcn_mfma_f32_16x16x32_bf16(al[ks], bh[ks][c], acc[c], 0, 0, 0);
            }
        }
        int rbase = (lane >> 4) * 4;
        #pragma unroll
        for (int c = 0; c < 2; ++c) {
            #pragma unroll
            for (int r = 0; r < 4; ++r)
                C[(size_t)(m0 + rbase + r) * 1024 + n0 + c * 16 + lr] = cvt_out<CT>(acc[c][r]);
        }
    }
}

// ---------------------------------------------------------------- GAT attention pieces
__global__ __launch_bounds__(256) void k_esed(const __half* __restrict__ hf,
                                              const float* __restrict__ asrc,
                                              const float* __restrict__ adst,
                                              float* __restrict__ es,
                                              float* __restrict__ ed) {
    int n = blockIdx.x;
    int h = threadIdx.x >> 6;
    int lane = threadIdx.x & 63;
    const __half* hp = hf + (size_t)n * 1024 + h * 256;
    float s = 0.f, d2 = 0.f;
    for (int d = lane; d < 256; d += 64) {
        float v = __half2float(hp[d]);
        s  += v * asrc[h * 256 + d];
        d2 += v * adst[h * 256 + d];
    }
    #pragma unroll
    for (int off = 32; off; off >>= 1) {
        s  += __shfl_down(s, off);
        d2 += __shfl_down(d2, off);
    }
    if (lane == 0) { es[n * 4 + h] = s; ed[n * 4 + h] = d2; }
}

// fused GAT aggregation via CSR gather; optionally emits fp32 and/or bf16 hi/lo outputs
template <bool EMIT_F32, bool EMIT_BF>
__global__ __launch_bounds__(256) void k_gat(const int* __restrict__ rowptr,
                                             const int* __restrict__ csrc,
                                             const float* __restrict__ es,
                                             const float* __restrict__ ed,
                                             const __half* __restrict__ hf,
                                             const float* __restrict__ bias,
                                             float* __restrict__ hout,
                                             unsigned short* __restrict__ oh,
                                             unsigned short* __restrict__ ol) {
    __shared__ float sm[4][256];
    int dst = blockIdx.x;
    int h = threadIdx.x >> 6, lane = threadIdx.x & 63;
    int r0 = rowptr[dst], r1 = rowptr[dst + 1];
    float edv = ed[dst * 4 + h];
    float vself = leaky(es[dst * 4 + h] + edv);
    float m = vself;
    for (int r = r0; r < r1; ++r) {
        int src = csrc[r];
        m = fmaxf(m, leaky(es[src * 4 + h] + edv));
    }
    float w = __expf(vself - m);
    float den = w;
    const __half2* hp2 = (const __half2*)(hf + (size_t)dst * 1024 + h * 256);
    __half2 p0 = hp2[lane * 2], p1 = hp2[lane * 2 + 1];
    float2 f0 = __half22float2(p0), f1 = __half22float2(p1);
    float4 acc;
    acc.x = w * f0.x; acc.y = w * f0.y; acc.z = w * f1.x; acc.w = w * f1.y;
    for (int r = r0; r < r1; ++r) {
        int src = csrc[r];
        float v = leaky(es[src * 4 + h] + edv);
        w = __expf(v - m);
        den += w;
        const __half2* sp2 = (const __half2*)(hf + (size_t)src * 1024 + h * 256);
        __half2 s0 = sp2[lane * 2], s1 = sp2[lane * 2 + 1];
        float2 g0 = __half22float2(s0), g1 = __half22float2(s1);
        acc.x += w * g0.x; acc.y += w * g0.y; acc.z += w * g1.x; acc.w += w * g1.y;
    }
    float inv = 1.f / (den + 1e-16f);
    sm[h][lane * 4 + 0] = acc.x * inv;
    sm[h][lane * 4 + 1] = acc.y * inv;
    sm[h][lane * 4 + 2] = acc.z * inv;
    sm[h][lane * 4 + 3] = acc.w * inv;
    __syncthreads();
    int d = threadIdx.x;
    float s = 0.25f * (sm[0][d] + sm[1][d] + sm[2][d] + sm[3][d]) + bias[d];
    float v = fmaxf(s, 0.f);
    if (EMIT_F32) hout[(size_t)dst * 256 + d] = v;
    if (EMIT_BF) {
        unsigned short hi = f2bf(v);
        oh[(size_t)dst * 256 + d] = hi;
        ol[(size_t)dst * 256 + d] = f2bf(v - bf2f(hi));
    }
}

// ---------------------------------------------------------------- heads
__global__ __launch_bounds__(256) void k_wire(const int* __restrict__ wm,
                                              const float* __restrict__ h2,
                                              const float* __restrict__ ww,
                                              const float* __restrict__ wb,
                                              float* __restrict__ out) {
    int k = blockIdx.x * 4 + (threadIdx.x >> 6);
    int lane = threadIdx.x & 63;
    if (k >= KWIRE) return;
    int n = wm[k];
    float s = 0.f;
    for (int d = lane; d < 256; d += 64) s += h2[(size_t)n * 256 + d] * ww[d];
    #pragma unroll
    for (int off = 32; off; off >>= 1) s += __shfl_down(s, off);
    if (lane == 0) out[k] = s + wb[0];
}

// segmented pooling: batch is sorted -> register runs + one atomic per boundary
__global__ __launch_bounds__(256) void k_pool(const float* __restrict__ h2,
                                              const int* __restrict__ batch,
                                              float* __restrict__ pooled,
                                              float* __restrict__ gcnt) {
    int n0 = blockIdx.x * POOL_NB;
    int n1 = n0 + POOL_NB; if (n1 > N_NODES) n1 = N_NODES;
    int d = threadIdx.x;
    int cur = batch[n0];
    float acc = 0.f, cnt = 0.f;
    for (int n = n0; n < n1; ++n) {
        int g = batch[n];
        if (g != cur) {
            atomicAdd(&pooled[cur * 256 + d], acc);
            if (d == 0) atomicAdd(&gcnt[cur], cnt);
            acc = 0.f; cnt = 0.f; cur = g;
        }
        acc += h2[(size_t)n * 256 + d];
        cnt += 1.f;
    }
    atomicAdd(&pooled[cur * 256 + d], acc);
    if (d == 0) atomicAdd(&gcnt[cur], cnt);
}

__global__ __launch_bounds__(256) void k_act(const float* __restrict__ pooled,
                                             const float* __restrict__ gcnt,
                                             const float* __restrict__ aw,
                                             const float* __restrict__ ab,
                                             float* __restrict__ out) {
    int u = blockIdx.x * 4 + (threadIdx.x >> 6);
    int lane = threadIdx.x & 63;
    if (u >= NGRAPH * NACT) return;
    int g = u >> 4, a = u & 15;
    float c = fmaxf(gcnt[g], 1.f);
    float s = 0.f;
    for (int d = lane; d < 256; d += 64) s += pooled[g * 256 + d] * aw[d * 16 + a];
    #pragma unroll
    for (int off = 32; off; off >>= 1) s += __shfl_down(s, off);
    if (lane == 0) out[KWIRE + u] = s / c + ab[a];
}

// ---------------------------------------------------------------- launch
extern "C" void kernel_launch(void* const* d_in, const int* in_sizes, int n_in,
                              void* d_out, int out_size, void* d_ws, size_t ws_size,
                              hipStream_t stream) {
    const float* x        = (const float*)d_in[0];
    const float* edge_attr= (const float*)d_in[1];
    const int*   wire_mask= (const int*)d_in[2];
    const int*   edge_idx = (const int*)d_in[3];
    const int*   batch    = (const int*)d_in[4];
    const float* enc_w1   = (const float*)d_in[5];
    const float* enc_b1   = (const float*)d_in[6];
    const float* enc_w2   = (const float*)d_in[7];
    const float* enc_b2   = (const float*)d_in[8];
    const float* root_w   = (const float*)d_in[9];
    const float* nn_bias  = (const float*)d_in[10];
    const float* gat1_w   = (const float*)d_in[11];
    const float* gat1_asrc= (const float*)d_in[12];
    const float* gat1_adst= (const float*)d_in[13];
    const float* gat1_b   = (const float*)d_in[14];
    const float* gat2_w   = (const float*)d_in[15];
    const float* gat2_asrc= (const float*)d_in[16];
    const float* gat2_adst= (const float*)d_in[17];
    const float* gat2_b   = (const float*)d_in[18];
    const float* wire_w   = (const float*)d_in[19];
    const float* wire_b   = (const float*)d_in[20];
    const float* act_w    = (const float*)d_in[21];
    const float* act_b    = (const float*)d_in[22];
    float* out = (float*)d_out;

    float* ws = (float*)d_ws;
    size_t off = 0;
    __half* T16    = (__half*)(ws + off); off += (size_t)M_PAD * 1024 / 2;   // 51.2 MB
    __half* hfrag  = (__half*)(ws + off); off += (size_t)M_PAD * 1024 / 2;   // 51.2 MB
    float* xb     = ws + off; off += 800000;
    float* agg    = ws + off; off += 800000;
    float* cntf   = ws + off; off += 25600;
    float* esb    = ws + off; off += 100000;
    float* edb    = ws + off; off += 100000;
    float* h2     = ws + off; off += 6400000;
    float* pooled = ws + off; off += NGRAPH * 256;
    float* gcnt   = ws + off; off += NGRAPH;
    int* deg      = (int*)(ws + off); off += 25600;
    int* rowptr   = (int*)(ws + off); off += 25600;
    int* cursor   = (int*)(ws + off); off += 25600;
    int* csrc     = (int*)(ws + off); off += N_EDGES;
    unsigned short* w1h = (unsigned short*)(ws + off); off += 16384;  // gat1_w [1024][32]
    unsigned short* w1l = (unsigned short*)(ws + off); off += 16384;
    unsigned short* w2h = (unsigned short*)(ws + off); off += 131072; // gat2_w [1024][256]
    unsigned short* w2l = (unsigned short*)(ws + off); off += 131072;
    unsigned short* wth = (unsigned short*)(ws + off); off += 16384;  // enc_w2 perm [1024][32]
    unsigned short* wtl = (unsigned short*)(ws + off); off += 16384;
    unsigned short* xh  = (unsigned short*)(ws + off); off += (size_t)M_PAD * 32 / 2;
    unsigned short* xl  = (unsigned short*)(ws + off); off += (size_t)M_PAD * 32 / 2;
    unsigned short* h0h = (unsigned short*)(ws + off); off += (size_t)M_PAD * 32 / 2;
    unsigned short* h0l = (unsigned short*)(ws + off); off += (size_t)M_PAD * 32 / 2;
    unsigned short* h1h = (unsigned short*)(ws + off); off += (size_t)M_PAD * 256 / 2;
    unsigned short* h1l = (unsigned short*)(ws + off); off += (size_t)M_PAD * 256 / 2;

    // ---- CSR build (by dst) ----
    hipMemsetAsync(deg, 0, 25600 * sizeof(int), stream);
    hipMemsetAsync(cursor, 0, 25600 * sizeof(int), stream);
    k_deg<<<(N_EDGES + 255) / 256, 256, 0, stream>>>(edge_idx, deg);
    k_scan<<<1, 256, 0, stream>>>(deg, rowptr);
    k_scatter<<<(N_EDGES + 255) / 256, 256, 0, stream>>>(edge_idx, rowptr, cursor, csrc);

    // ---- weight prep ----
    k_wsplit<IN_DIM><<<(IN_DIM * 1024 + 255) / 256, 256, 0, stream>>>(gat1_w, w1h, w1l);
    k_wsplit<HIDD><<<(HIDD * 1024 + 255) / 256, 256, 0, stream>>>(gat2_w, w2h, w2l);
    k_w2perm<<<(32 * 1024 + 255) / 256, 256, 0, stream>>>(enc_w2, wth, wtl);
    k_xsplit<<<(N_NODES * 32 + 255) / 256, 256, 0, stream>>>(x, enc_b2, xh, xl, xb);

    // ---- NNConv: T = x @ W2perm (MFMA), then edge pass ----
    hipMemsetAsync(agg, 0, (800000 + 25600) * sizeof(float), stream);
    {
        dim3 g(8, (M_PAD / 16 + 24) / 25);
        k_mfmm<IN_DIM, 25, __half><<<g, 256, 0, stream>>>(xh, xl, wth, wtl, T16);
    }
    k_msg<<<N_EDGES / 8, 256, 0, stream>>>(edge_attr, enc_w1, enc_b1, edge_idx, T16, xb, agg, cntf);
    k_h0<<<N_NODES / 8, 256, 0, stream>>>(x, root_w, nn_bias, agg, cntf, h0h, h0l);

    // ---- GAT layer 1: hfrag = h0 @ gat1_w ----
    {
        dim3 g(8, (M_PAD / 16 + 24) / 25);
        k_mfmm<IN_DIM, 25, __half><<<g, 256, 0, stream>>>(h0h, h0l, w1h, w1l, hfrag);
    }
    k_esed<<<N_NODES, 256, 0, stream>>>(hfrag, gat1_asrc, gat1_adst, esb, edb);
    k_gat<false, true><<<N_NODES, 256, 0, stream>>>(rowptr, csrc, esb, edb, hfrag, gat1_b,
                                                    nullptr, h1h, h1l);

    // ---- GAT layer 2: hfrag = h1 @ gat2_w ----
    {
        dim3 g(8, (M_PAD / 16 + 24) / 25);
        k_mfmm<HIDD, 25, __half><<<g, 256, 0, stream>>>(h1h, h1l, w2h, w2l, hfrag);
    }
    k_esed<<<N_NODES, 256, 0, stream>>>(hfrag, gat2_asrc, gat2_adst, esb, edb);
    k_gat<true, false><<<N_NODES, 256, 0, stream>>>(rowptr, csrc, esb, edb, hfrag, gat2_b,
                                                    h2, nullptr, nullptr);

    // ---- heads ----
    k_wire<<<KWIRE / 4, 256, 0, stream>>>(wire_mask, h2, wire_w, wire_b, out);
    hipMemsetAsync(pooled, 0, (NGRAPH * 256 + NGRAPH) * sizeof(float), stream);
    k_pool<<<(N_NODES + POOL_NB - 1) / POOL_NB, 256, 0, stream>>>(h2, batch, pooled, gcnt);
    k_act<<<NGRAPH * NACT / 4, 256, 0, stream>>>(pooled, gcnt, act_w, act_b, out);
}